// Round 3
// 534.828 us; speedup vs baseline: 1.0147x; 1.0147x over previous
//
#include <hip/hip_runtime.h>
#include <hip/hip_bf16.h>

#define BQ 4
#define LQ 4096
#define HID 1024
#define NHEAD 8
#define DHEAD 128
#define MROWS (BQ * LQ) /* 16384 */
#define CCH 64          /* chunk length */
#define NCH (LQ / CCH)  /* 64 chunks */
#define GNT 16          /* K-tiles of 64 in the 256^2 GEMMs */

typedef __bf16 bf16x8 __attribute__((ext_vector_type(8)));
typedef float f32x4 __attribute__((ext_vector_type(4)));

__device__ __forceinline__ float bf2f(unsigned short u) {
    return __uint_as_float(((unsigned int)u) << 16);
}
__device__ __forceinline__ unsigned short f2us(float f) {
    __hip_bfloat16 b = __float2bfloat16(f);
    return *reinterpret_cast<unsigned short*>(&b);
}
__device__ __forceinline__ float loadAny(const void* p, size_t i, bool isf) {
    return isf ? ((const float*)p)[i] : bf2f(((const unsigned short*)p)[i]);
}

// ---------------------------------------------------------------------------
// Dtype probe: flag=1 -> inputs are f32; flag=0 -> bf16.
// ---------------------------------------------------------------------------
__global__ void detect_kernel(const void* x, int* flag) {
    const unsigned short* u = (const unsigned short*)x;
    int t = threadIdx.x;  // 64 threads
    int cnt = 0;
#pragma unroll
    for (int s = 0; s < 64; ++s) {
        unsigned short v = u[2 * (t * 64 + s)];
        int e = (v >> 7) & 0xFF;
        cnt += (e >= 0x8A || (e != 0 && e <= 0x6E)) ? 1 : 0;
    }
#pragma unroll
    for (int m = 1; m < 64; m <<= 1) cnt += __shfl_xor(cnt, m);
    if (t == 0) *flag = (cnt > 1024) ? 1 : 0;
}

// ---------------------------------------------------------------------------
// Convert the four 1024x1024 weights to bf16; blockIdx.y==4 builds RoPE tables.
// ---------------------------------------------------------------------------
__global__ __launch_bounds__(256) void cvt_w4_kernel(
    const void* Wq, const void* Wk, const void* Wv, const void* Wout,
    unsigned short* dq, unsigned short* dk, unsigned short* dv, unsigned short* dout,
    float* __restrict__ cosT, float* __restrict__ sinT,
    const int* flagp) {
    if (blockIdx.y == 4) {
        int idx = blockIdx.x * 256 + threadIdx.x;  // 0..262143 = 4096*64
        int l = idx >> 6, i = idx & 63;
        float invf = powf(10000.0f, -(float)i * (1.0f / 64.0f));
        float fr = (float)l * invf;
        cosT[idx] = cosf(fr);
        sinT[idx] = sinf(fr);
        return;
    }
    const bool isf = (*flagp != 0);
    const void* s;
    unsigned short* d;
    switch (blockIdx.y) {
        case 0: s = Wq; d = dq; break;
        case 1: s = Wk; d = dk; break;
        case 2: s = Wv; d = dv; break;
        default: s = Wout; d = dout; break;
    }
    size_t i = ((size_t)blockIdx.x * 256 + threadIdx.x) * 4;
#pragma unroll
    for (int r = 0; r < 4; ++r) d[i + r] = f2us(loadAny(s, i + r, isf));
}

// ---------------------------------------------------------------------------
// Convert gate weights (3 x 8x1024 -> bf16) and biases (-> f32).
// ---------------------------------------------------------------------------
__global__ __launch_bounds__(256) void cvt_small_kernel(
    const void* Wbeta, const void* Wig, const void* Wog,
    const void* bbeta, const void* big, const void* bog, const void* bout,
    unsigned short* dWb, unsigned short* dWi, unsigned short* dWo,
    float* dbb, float* dbi, float* dbo, float* dbout,
    const int* flagp) {
    const bool isf = (*flagp != 0);
    int gid = blockIdx.x * 256 + threadIdx.x;
    if (gid < 24576) {
        int seg = gid >> 13, off = gid & 8191;
        const void* s = (seg == 0) ? Wbeta : (seg == 1) ? Wig : Wog;
        unsigned short* d = (seg == 0) ? dWb : (seg == 1) ? dWi : dWo;
        d[off] = f2us(loadAny(s, off, isf));
    } else {
        int j = gid - 24576;
        if (j < 8) dbb[j] = loadAny(bbeta, j, isf);
        else if (j < 16) dbi[j - 8] = loadAny(big, j - 8, isf);
        else if (j < 24) dbo[j - 16] = loadAny(bog, j - 16, isf);
        else if (j < 24 + 1024) dbout[j - 24] = loadAny(bout, j - 24, isf);
    }
}

// ---------------------------------------------------------------------------
// Fused RMSNorm + gates: h = x*rsqrt(mean(x^2)+1e-6)*w (bf16 out), and the
// 24 sigmoid gates computed from the normalized row held in registers.
// ---------------------------------------------------------------------------
__global__ __launch_bounds__(256) void rmsnorm_gates_kernel(
    const void* __restrict__ xin, const void* __restrict__ win,
    __hip_bfloat16* __restrict__ h, const int* __restrict__ flagp,
    const __hip_bfloat16* __restrict__ Wbeta, const float* __restrict__ bbeta,
    const __hip_bfloat16* __restrict__ Wig, const float* __restrict__ big,
    const __hip_bfloat16* __restrict__ Wog, const float* __restrict__ bog,
    float* __restrict__ fT, float* __restrict__ gT, float* __restrict__ oT) {
    const bool isf = (*flagp != 0);
    const int row = blockIdx.x;
    const int tid = threadIdx.x;
    const int lane = tid & 63, wave = tid >> 6;
    const int b = row >> 12, l = row & (LQ - 1);
    const size_t base = (size_t)row * HID;
    float x0, x1, x2, x3;
    if (isf) {
        float4 u = ((const float4*)((const float*)xin + base))[tid];
        x0 = u.x; x1 = u.y; x2 = u.z; x3 = u.w;
    } else {
        ushort4 u = ((const ushort4*)((const unsigned short*)xin + base))[tid];
        x0 = bf2f(u.x); x1 = bf2f(u.y); x2 = bf2f(u.z); x3 = bf2f(u.w);
    }
    float ss = x0 * x0 + x1 * x1 + x2 * x2 + x3 * x3;
#pragma unroll
    for (int m = 1; m < 64; m <<= 1) ss += __shfl_xor(ss, m);
    __shared__ float wsum[4];
    if (lane == 0) wsum[wave] = ss;
    __syncthreads();
    float tot = wsum[0] + wsum[1] + wsum[2] + wsum[3];
    float inv = rsqrtf(tot * (1.0f / HID) + 1e-6f);
    float w0, w1, w2, w3;
    if (isf) {
        float4 u = ((const float4*)win)[tid];
        w0 = u.x; w1 = u.y; w2 = u.z; w3 = u.w;
    } else {
        ushort4 u = ((const ushort4*)win)[tid];
        w0 = bf2f(u.x); w1 = bf2f(u.y); w2 = bf2f(u.z); w3 = bf2f(u.w);
    }
    float h0 = x0 * inv * w0, h1 = x1 * inv * w1, h2 = x2 * inv * w2, h3 = x3 * inv * w3;
    __hip_bfloat16* ho = h + base + tid * 4;
    ho[0] = __float2bfloat16(h0);
    ho[1] = __float2bfloat16(h1);
    ho[2] = __float2bfloat16(h2);
    ho[3] = __float2bfloat16(h3);
    // gates from register h
    float p[24];
#pragma unroll
    for (int g = 0; g < 24; ++g) {
        const __hip_bfloat16* wr = (g < 8) ? (Wbeta + g * HID)
                                 : (g < 16) ? (Wig + (g - 8) * HID)
                                            : (Wog + (g - 16) * HID);
        const unsigned short* wp = (const unsigned short*)wr + tid * 4;
        ushort4 wu = *(const ushort4*)wp;
        p[g] = h0 * bf2f(wu.x) + h1 * bf2f(wu.y) + h2 * bf2f(wu.z) + h3 * bf2f(wu.w);
    }
#pragma unroll
    for (int m = 1; m < 64; m <<= 1) {
#pragma unroll
        for (int g = 0; g < 24; ++g) p[g] += __shfl_xor(p[g], m);
    }
    __shared__ float part[4][24];
    if (lane == 0) {
#pragma unroll
        for (int g = 0; g < 24; ++g) part[wave][g] = p[g];
    }
    __syncthreads();
    if (tid < 24) {
        int g = tid;
        float s = part[0][g] + part[1][g] + part[2][g] + part[3][g];
        float bb = (g < 8) ? bbeta[g] : (g < 16) ? big[g - 8] : bog[g - 16];
        s += bb;
        s = 1.0f / (1.0f + expf(-s));
        int hh = (g < 8) ? g : (g < 16) ? g - 8 : g - 16;
        float* dst = (g < 8) ? fT : (g < 16) ? gT : oT;
        dst[((size_t)(b * NHEAD + hh)) * LQ + l] = s;
    }
}

// ---------------------------------------------------------------------------
// 256x256 (BK=64) 8-wave 4-phase GEMM core, conservative double-buffer
// discipline (race-screen-safe rework of the round-0 schedule).
//
//   * Staging ONLY ever targets the NEXT buffer (holds tile t-1's data,
//     fully read and fully landed before tile t's first stage issues).
//     No writes to the in-use buffer -> no overwrite-while-readable hazard.
//   * Stage order A0,B0,B1,A1 matches first-read order of tile t+1
//     (ph0 reads A0,B0; ph1 reads B1; ph2 reads A1).  Counted waits certify
//     each half before its first reader:
//       invariant: enter tile t with 4 outstanding loads = (t).B1,(t).A1
//       ph0-close  vmcnt(4)  -> (t).B1 landed   (outstanding 6 -> 4)
//       ph1-close  vmcnt(4)  -> (t).A1 landed   (6 -> 4)
//       ph3-close  vmcnt(4)  -> (t+1).A0,B0 landed (8 -> 4 = invariant)
//     tail tile: vmcnt(2) / vmcnt(0) at ph0/ph1-close.
//   * Every s_barrier and waitcnt asm is sealed with sched_barrier(0) on
//     BOTH sides; explicit lgkmcnt(0) before the MFMA cluster (rule #18).
//   * T2 granule-XOR swizzle: 16B granule g of row r lives at g^(r&7);
//     global_load_lds dest stays linear, SOURCE address pre-swizzled,
//     ds_read applies the same XOR (both-sides rule, m104/m173).
//   * T5 setprio(1) around each 16-MFMA cluster.
// ---------------------------------------------------------------------------
__device__ __forceinline__ void g256_stage_half(const unsigned short* __restrict__ src,
                                                unsigned short* lds, int tid) {
#pragma unroll
    for (int l = 0; l < 2; ++l) {
        int L = l * 512 + tid;          // 1024 granules = 128 rows x 8
        int r = L >> 3, g = L & 7;
        int gs = g ^ (r & 7);           // pre-swizzled global source
        __builtin_amdgcn_global_load_lds(
            (const __attribute__((address_space(1))) void*)(src + (size_t)r * HID + gs * 8),
            (__attribute__((address_space(3))) void*)(lds + L * 8), 16, 0, 0);
    }
}

#define G256_SEAL() __builtin_amdgcn_sched_barrier(0)
#define G256_BARRIER()            \
    do {                          \
        G256_SEAL();              \
        __builtin_amdgcn_s_barrier(); \
        G256_SEAL();              \
    } while (0)

__device__ __forceinline__ void g256_core(const unsigned short* __restrict__ A,
                                          const unsigned short* __restrict__ W,
                                          unsigned short* As, unsigned short* Bs,
                                          int m0, int tid, f32x4 (&acc)[8][4]) {
    const int lane = tid & 63, wid = tid >> 6;
    const int wr = wid >> 2, wc = wid & 3;
    const int lm = lane & 15, lq = lane >> 4;
    // prologue: tile0 all 4 halves -> buf0, full drain, barrier.
    g256_stage_half(A + (size_t)m0 * HID, As, tid);                  // A0
    g256_stage_half(W, Bs, tid);                                     // B0
    g256_stage_half(W + (size_t)128 * HID, Bs + 8192, tid);          // B1
    g256_stage_half(A + (size_t)(m0 + 128) * HID, As + 8192, tid);   // A1
    G256_SEAL();
    asm volatile("s_waitcnt vmcnt(0)" ::: "memory");
    G256_BARRIER();
    for (int t = 0; t < GNT; ++t) {
        unsigned short* Ac = As + (t & 1) * 16384;
        unsigned short* Bc = Bs + (t & 1) * 16384;
        unsigned short* An = As + ((t & 1) ^ 1) * 16384;
        unsigned short* Bn = Bs + ((t & 1) ^ 1) * 16384;
        const int kn = (t + 1) * 64;
        const bool pf = (t + 1 < GNT);
#pragma unroll
        for (int ph = 0; ph < 4; ++ph) {
            const int mq = ph >> 1, nq = ph & 1;
            // ds_reads for this phase (swizzled)
            bf16x8 af[4][2], bfr[2][2];
#pragma unroll
            for (int i = 0; i < 4; ++i) {
                const int row = mq * 128 + wr * 64 + i * 16 + lm;
#pragma unroll
                for (int kk = 0; kk < 2; ++kk) {
                    const int gsw = (kk * 4 + lq) ^ (lm & 7);
                    af[i][kk] = *(const bf16x8*)(const void*)(Ac + row * 64 + gsw * 8);
                }
            }
#pragma unroll
            for (int j = 0; j < 2; ++j) {
                const int row = nq * 128 + wc * 32 + j * 16 + lm;
#pragma unroll
                for (int kk = 0; kk < 2; ++kk) {
                    const int gsw = (kk * 4 + lq) ^ (lm & 7);
                    bfr[j][kk] = *(const bf16x8*)(const void*)(Bc + row * 64 + gsw * 8);
                }
            }
            // stage one half of tile t+1 into the NEXT buffer only
            if (pf) {
                if (ph == 0) g256_stage_half(A + (size_t)m0 * HID + kn, An, tid);
                if (ph == 1) g256_stage_half(W + kn, Bn, tid);
                if (ph == 2) g256_stage_half(W + (size_t)128 * HID + kn, Bn + 8192, tid);
                if (ph == 3) g256_stage_half(A + (size_t)(m0 + 128) * HID + kn, An + 8192, tid);
            }
            G256_BARRIER();
            asm volatile("s_waitcnt lgkmcnt(0)" ::: "memory");
            G256_SEAL();
            __builtin_amdgcn_s_setprio(1);
#pragma unroll
            for (int i = 0; i < 4; ++i)
#pragma unroll
                for (int j = 0; j < 2; ++j)
#pragma unroll
                    for (int kk = 0; kk < 2; ++kk)
                        acc[mq * 4 + i][nq * 2 + j] = __builtin_amdgcn_mfma_f32_16x16x32_bf16(
                            af[i][kk], bfr[j][kk], acc[mq * 4 + i][nq * 2 + j], 0, 0, 0);
            __builtin_amdgcn_s_setprio(0);
            G256_SEAL();
            // counted waits certifying landings before their reader phases
            if (ph == 0) {
                if (pf) asm volatile("s_waitcnt vmcnt(4)" ::: "memory");
                else    asm volatile("s_waitcnt vmcnt(2)" ::: "memory");
            } else if (ph == 1) {
                if (pf) asm volatile("s_waitcnt vmcnt(4)" ::: "memory");
                else    asm volatile("s_waitcnt vmcnt(0)" ::: "memory");
            } else if (ph == 3) {
                if (pf) asm volatile("s_waitcnt vmcnt(4)" ::: "memory");
            }
            G256_BARRIER();
        }
    }
}

// ---------------------------------------------------------------------------
// Merged QKV GEMM on the 256^2 core: blockIdx.y in [0,12) -> weight y>>2,
// column block (y&3)*256.
// ---------------------------------------------------------------------------
__global__ __launch_bounds__(512) void gemm_qkv(const __hip_bfloat16* __restrict__ A,
                                                const unsigned short* __restrict__ Wqc,
                                                const unsigned short* __restrict__ Wkc,
                                                const unsigned short* __restrict__ Wvc,
                                                unsigned short* __restrict__ qb,
                                                unsigned short* __restrict__ kb,
                                                unsigned short* __restrict__ vb) {
    __shared__ __align__(16) unsigned short As[2 * 16384];
    __shared__ __align__(16) unsigned short Bs[2 * 16384];
    const int nblk = blockIdx.y;
    const int sel = nblk >> 2;
    const int nl0 = (nblk & 3) * 256;
    const unsigned short* W = (sel == 0 ? Wqc : sel == 1 ? Wkc : Wvc) + (size_t)nl0 * HID;
    unsigned short* C = (sel == 0) ? qb : (sel == 1) ? kb : vb;
    const int tid = threadIdx.x;
    const int lane = tid & 63, wid = tid >> 6;
    const int wr = wid >> 2, wc = wid & 3;
    const int lm = lane & 15, lq = lane >> 4;
    const int m0 = blockIdx.x * 256;
    f32x4 acc[8][4] = {};
    g256_core((const unsigned short*)A, W, As, Bs, m0, tid, acc);
#pragma unroll
    for (int mq = 0; mq < 2; ++mq)
#pragma unroll
        for (int i = 0; i < 4; ++i)
#pragma unroll
            for (int nq = 0; nq < 2; ++nq)
#pragma unroll
                for (int j = 0; j < 2; ++j) {
                    const int col = nl0 + nq * 128 + wc * 32 + j * 16 + lm;
#pragma unroll
                    for (int r = 0; r < 4; ++r) {
                        const int rowg = m0 + mq * 128 + wr * 64 + i * 16 + lq * 4 + r;
                        C[(size_t)rowg * HID + col] = f2us(acc[mq * 4 + i][nq * 2 + j][r]);
                    }
                }
}

// ---------------------------------------------------------------------------
// Final GEMM on the 256^2 core: C = A W^T + bias; C f32 when (*flagp).
// ---------------------------------------------------------------------------
__global__ __launch_bounds__(512) void gemm_bt(const __hip_bfloat16* __restrict__ A,
                                               const __hip_bfloat16* __restrict__ W,
                                               const float* __restrict__ bias,
                                               void* __restrict__ C,
                                               const int* __restrict__ flagp) {
    __shared__ __align__(16) unsigned short As[2 * 16384];
    __shared__ __align__(16) unsigned short Bs[2 * 16384];
    const bool f32out = (*flagp != 0);
    const int tid = threadIdx.x;
    const int lane = tid & 63, wid = tid >> 6;
    const int wr = wid >> 2, wc = wid & 3;
    const int lm = lane & 15, lq = lane >> 4;
    const int m0 = blockIdx.x * 256;
    const int nl0 = blockIdx.y * 256;
    f32x4 acc[8][4] = {};
    g256_core((const unsigned short*)A, (const unsigned short*)W + (size_t)nl0 * HID,
              As, Bs, m0, tid, acc);
#pragma unroll
    for (int mq = 0; mq < 2; ++mq)
#pragma unroll
        for (int i = 0; i < 4; ++i)
#pragma unroll
            for (int nq = 0; nq < 2; ++nq)
#pragma unroll
                for (int j = 0; j < 2; ++j) {
                    const int col = nl0 + nq * 128 + wc * 32 + j * 16 + lm;
                    const float bv = bias[col];
#pragma unroll
                    for (int r = 0; r < 4; ++r) {
                        const int rowg = m0 + mq * 128 + wr * 64 + i * 16 + lq * 4 + r;
                        const size_t idx = (size_t)rowg * HID + col;
                        const float val = acc[mq * 4 + i][nq * 2 + j][r] + bv;
                        if (f32out) ((float*)C)[idx] = val;
                        else ((__hip_bfloat16*)C)[idx] = __float2bfloat16(val);
                    }
                }
}

// ---------------------------------------------------------------------------
// INTRA kernel + prep. Q is never staged to LDS: each lane builds its MFMA
// A-fragment of rope(q) in registers (pair i/i+64 lives in the same thread)
// and writes scaled qb back from the same registers. LDS = Kr+Vt+Sp ~46 KB
// -> 3 blocks/CU (was 2).
// ---------------------------------------------------------------------------
__global__ __launch_bounds__(256) void intra_kernel(
    unsigned short* __restrict__ qg, const unsigned short* __restrict__ kg,
    const unsigned short* __restrict__ vg,
    const float* __restrict__ fT, const float* __restrict__ gT, const float* __restrict__ oT,
    const float* __restrict__ cosT, const float* __restrict__ sinT,
    __hip_bfloat16* __restrict__ yb,
    unsigned short* __restrict__ ktg, float* __restrict__ cdecG) {
    const int chunk = blockIdx.x;        // 0..63
    const int bh = blockIdx.y;           // 0..31
    const int b = bh >> 3, hh = bh & 7;
    const int t0 = chunk * CCH;
    const int tid = threadIdx.x;
    const int lane = tid & 63, wave = tid >> 6;
    const int lm = lane & 15, lq = lane >> 4;
    __shared__ unsigned short Kr[64 * 136];
    __shared__ unsigned short Vt[128 * 72];
    __shared__ unsigned short Sp[64 * 72];
    __shared__ float Lp[64], aS[64], osh[64], w2s[64], qscs[64];

    // phase 0: gates + decay prefix (wave 0)
    if (tid < 64) {
        float f = fT[(size_t)bh * LQ + t0 + tid];
        float g = gT[(size_t)bh * LQ + t0 + tid];
        osh[tid] = oT[(size_t)bh * LQ + t0 + tid];
        float lf = __logf(f);
#pragma unroll
        for (int off = 1; off < 64; off <<= 1) {
            float v = __shfl_up(lf, off);
            if (lane >= off) lf += v;
        }
        float tot = __shfl(lf, 63);
        Lp[tid] = lf;
        aS[tid] = g * 0.08838834764831845f;  // g / sqrt(128)
        w2s[tid] = __expf(tot - lf) * (g * 0.08838834764831845f);
        qscs[tid] = __expf(lf);
        if (tid == 63) cdecG[bh * NCH + chunk] = __expf(lf);
    }
    __syncthreads();  // B0

    // phase 1a: Q fragments in registers + scaled write-back.
    // Lane owns row (16*wave+lm), k-cols ks*32+lq*8+[0,8) for ks=0..3.
    bf16x8 af[4];
    {
        const int jr = 16 * wave + lm;
        const int gt = t0 + jr;
        const size_t qbase = ((size_t)(b * LQ + gt)) * HID + hh * DHEAD;
        uint4 qraw[4];
#pragma unroll
        for (int ks = 0; ks < 4; ++ks)
            qraw[ks] = *(const uint4*)(qg + qbase + ks * 32 + lq * 8);
        const unsigned short* q0 = (const unsigned short*)&qraw[0];
        const unsigned short* q1 = (const unsigned short*)&qraw[1];
        const unsigned short* q2 = (const unsigned short*)&qraw[2];
        const unsigned short* q3 = (const unsigned short*)&qraw[3];
        const float sc = qscs[jr];
        __align__(16) unsigned short fr[4][8];
        __align__(16) unsigned short qo[4][8];
#pragma unroll
        for (int u = 0; u < 8; ++u) {
            int i = lq * 8 + u;          // pair (i, i+64) for ks 0<->2
            int i2 = 32 + lq * 8 + u;    // pair for ks 1<->3
            float c0 = cosT[gt * 64 + i], s0 = sinT[gt * 64 + i];
            float c1 = cosT[gt * 64 + i2], s1 = sinT[gt * 64 + i2];
            float a = bf2f(q0[u]), bq = bf2f(q2[u]);
            float rc = a * c0 - bq * s0, rs = a * s0 + bq * c0;
            fr[0][u] = f2us(rc); fr[2][u] = f2us(rs);
            qo[0][u] = f2us(rc * sc); qo[2][u] = f2us(rs * sc);
            float a1 = bf2f(q1[u]), bq1 = bf2f(q3[u]);
            float rc1 = a1 * c1 - bq1 * s1, rs1 = a1 * s1 + bq1 * c1;
            fr[1][u] = f2us(rc1); fr[3][u] = f2us(rs1);
            qo[1][u] = f2us(rc1 * sc); qo[3][u] = f2us(rs1 * sc);
        }
#pragma unroll
        for (int ks = 0; ks < 4; ++ks) {
            af[ks] = *(const bf16x8*)fr[ks];
            *(uint4*)(qg + qbase + ks * 32 + lq * 8) = *(const uint4*)qo[ks];
        }
    }
    // phase 1b: rope-stage K into LDS
#pragma unroll
    for (int r = 0; r < 16; ++r) {
        int pid = r * 256 + tid;
        int t = pid >> 6, i = pid & 63;
        int gt = t0 + t;
        size_t gidx = ((size_t)(b * LQ + gt)) * HID + hh * DHEAD + i;
        float c = cosT[gt * 64 + i], s = sinT[gt * 64 + i];
        float k1 = bf2f(kg[gidx]), k2 = bf2f(kg[gidx + 64]);
        Kr[t * 136 + i] = f2us(k1 * c - k2 * s);
        Kr[t * 136 + i + 64] = f2us(k1 * s + k2 * c);
    }
    // stage V transposed: Vt[e][s]
#pragma unroll
    for (int r = 0; r < 32; ++r) {
        int lin = r * 256 + tid;
        int sI = lin >> 7, e = lin & 127;
        float val = bf2f(vg[((size_t)(b * LQ + t0 + sI)) * HID + hh * DHEAD + e]);
        Vt[e * 72 + sI] = f2us(val);
    }
    __syncthreads();  // B1

    // S = Q K^T (64x64, K=128); wave j-strip [16*wave,+16), Q from registers
    f32x4 sacc[4] = {};
#pragma unroll
    for (int ks = 0; ks < 4; ++ks) {
#pragma unroll
        for (int nt = 0; nt < 4; ++nt) {
            bf16x8 bf = *(const bf16x8*)(const void*)(Kr + (nt * 16 + lm) * 136 + ks * 32 + lq * 8);
            sacc[nt] = __builtin_amdgcn_mfma_f32_16x16x32_bf16(af[ks], bf, sacc[nt], 0, 0, 0);
        }
    }
    // mask + decay/gate scale, store S' bf16 [j][s]
#pragma unroll
    for (int nt = 0; nt < 4; ++nt) {
#pragma unroll
        for (int r = 0; r < 4; ++r) {
            int j = 16 * wave + lq * 4 + r;
            int s = nt * 16 + lm;
            float v = 0.0f;
            if (j >= s) v = sacc[nt][r] * __expf(Lp[j] - Lp[s]) * aS[s];
            Sp[j * 72 + s] = f2us(v);
        }
    }
    // PREP: KtG[ks][d][32] = w2_s * Kr[s][d]
    {
        unsigned short* krec = ktg + ((size_t)(bh * NCH + chunk)) * 8192;
#pragma unroll
        for (int r = 0; r < 2; ++r) {
            int lin16 = r * 256 + tid;
            int ks = lin16 >> 8;
            int d = (lin16 & 255) >> 1;
            int cc0 = (lin16 & 1) * 16;
            __align__(16) unsigned short out[16];
#pragma unroll
            for (int u = 0; u < 16; ++u) {
                int s = ks * 32 + cc0 + u;
                out[u] = f2us(w2s[s] * bf2f(Kr[s * 136 + d]));
            }
            uint4* dst = (uint4*)(krec + (size_t)lin16 * 16);
            dst[0] = *(const uint4*)(out);
            dst[1] = *(const uint4*)(out + 8);
        }
    }
    __syncthreads();  // B2

    // Y_intra = S' V  (64x128, K=64)
    f32x4 ya[8] = {};
#pragma unroll
    for (int ks = 0; ks < 2; ++ks) {
        bf16x8 afs = *(const bf16x8*)(const void*)(Sp + (16 * wave + lm) * 72 + ks * 32 + lq * 8);
#pragma unroll
        for (int nt = 0; nt < 8; ++nt) {
            bf16x8 bf = *(const bf16x8*)(const void*)(Vt + (nt * 16 + lm) * 72 + ks * 32 + lq * 8);
            ya[nt] = __builtin_amdgcn_mfma_f32_16x16x32_bf16(afs, bf, ya[nt], 0, 0, 0);
        }
    }
#pragma unroll
    for (int nt = 0; nt < 8; ++nt) {
#pragma unroll
        for (int r = 0; r < 4; ++r) {
            int j = 16 * wave + lq * 4 + r;
            int e = nt * 16 + lm;
            size_t row = (size_t)(b * LQ + t0 + j);
            yb[row * HID + hh * DHEAD + e] = __float2bfloat16(osh[j] * ya[nt][r]);
        }
    }
}

// ---------------------------------------------------------------------------
// INTER kernel: ONE barrier per chunk. State M double-buffered in LDS (read
// M[c&1], write M[(c+1)&1]) so no second barrier is needed; Q/K DMA for c+1
// issued AFTER the top barrier so it stays in flight through chunk c's
// compute and is drained by the NEXT barrier (true prefetch overlap).
// yb RMW values prefetched right after the barrier to hide their latency.
// ---------------------------------------------------------------------------
__global__ __launch_bounds__(256) void inter_kernel(
    const unsigned short* __restrict__ qs,   // exp(Lp_j)*rope(q), [row][128]
    const unsigned short* __restrict__ ktg,  // [bh][chunk][ks][d][32]
    const unsigned short* __restrict__ vg,
    const float* __restrict__ oT, const float* __restrict__ cdecG,
    unsigned short* __restrict__ yb) {
    const int bh = blockIdx.x;       // 0..31
    const int esplit = blockIdx.y;   // 0..7
    const int e0 = esplit * 16;
    const int b = bh >> 3, hh = bh & 7;
    const int tid = threadIdx.x;
    const int lane = tid & 63, wave = tid >> 6;
    const int lm = lane & 15, lq = lane >> 4;
    __shared__ __align__(16) unsigned short Qsl[2][8192];  // [ks(4)][j(64)][32]
    __shared__ __align__(16) unsigned short Ktl[2][8192];  // [ks(2)][d(128)][32]
    __shared__ __align__(16) unsigned short Vtl[2][1024];  // [ks(2)][e(16)][32]
    __shared__ __align__(16) float Ml[2][16 * 132];        // M^T [e][d], stride 132

    for (int i = tid; i < 16 * 132; i += 256) Ml[0][i] = 0.0f;

    const int jrow = tid >> 2;
    const int qcol = (tid & 3) * 8;
    // prologue: DMA chunk 0 into buf 0, VALU-stage V0
    {
        const unsigned short* qrow =
            qs + ((size_t)(b * LQ + jrow)) * HID + hh * DHEAD + qcol;
#pragma unroll
        for (int ks = 0; ks < 4; ++ks)
            __builtin_amdgcn_global_load_lds(
                (const __attribute__((address_space(1))) void*)(qrow + ks * 32),
                (__attribute__((address_space(3))) void*)(&Qsl[0][ks * 2048 + tid * 8]),
                16, 0, 0);
        const unsigned short* kbase = ktg + ((size_t)(bh * NCH)) * 8192 + tid * 8;
#pragma unroll
        for (int i = 0; i < 4; ++i)
            __builtin_amdgcn_global_load_lds(
                (const __attribute__((address_space(1))) void*)(kbase + i * 2048),
                (__attribute__((address_space(3))) void*)(&Ktl[0][i * 2048 + tid * 8]),
                16, 0, 0);
#pragma unroll
        for (int r = 0; r < 4; ++r) {
            int lin = r * 256 + tid;
            int s = lin >> 4, e = lin & 15;
            float val = bf2f(vg[((size_t)(b * LQ + s)) * HID + hh * DHEAD + e0 + e]);
            Vtl[0][(s >> 5) * 512 + e * 32 + (s & 31)] = f2us(val);
        }
    }

    for (int c = 0; c < NCH; ++c) {
        const int cur = c & 1, nxt = cur ^ 1;
        const int t0 = c * CCH;
        __syncthreads();  // drains chunk-c DMA (issued last iter), M[cur] visible
        // issue DMA for c+1 (drained at NEXT barrier -> overlaps this compute)
        if (c + 1 < NCH) {
            const int t0n = t0 + CCH;
            const unsigned short* qrow =
                qs + ((size_t)(b * LQ + t0n + jrow)) * HID + hh * DHEAD + qcol;
#pragma unroll
            for (int ks = 0; ks < 4; ++ks)
                __builtin_amdgcn_global_load_lds(
                    (const __attribute__((address_space(1))) void*)(qrow + ks * 32),
                    (__attribute__((address_space(3))) void*)(&Qsl[nxt][ks * 2048 + tid * 8]),
                    16, 0, 0);
            const unsigned short* kbase = ktg + ((size_t)(bh * NCH + c + 1)) * 8192 + tid * 8;
#pragma unroll
            for (int i = 0; i < 4; ++i)
                __builtin_amdgcn_global_load_lds(
                    (const __attribute__((address_space(1))) void*)(kbase + i * 2048),
                    (__attribute__((address_space(3))) void*)(&Ktl[nxt][i * 2048 + tid * 8]),
                    16, 0, 0);
        }
        // early yb/o prefetch (consumed after MFMAs)
        size_t yidx[4];
        unsigned short prevy[4];
        float osv[4];
#pragma unroll
        for (int r = 0; r < 4; ++r) {
            int j = 16 * wave + lq * 4 + r;
            yidx[r] = ((size_t)(b * LQ + t0 + j)) * HID + hh * DHEAD + e0 + lm;
            prevy[r] = yb[yidx[r]];
            osv[r] = oT[(size_t)bh * LQ + t0 + j];
        }
        const float cd = cdecG[bh * NCH + c];
        // U = K''^T V : wave d-strip [32*wave, +32)
        f32x4 uacc[2] = {};
#pragma unroll
        for (int ks = 0; ks < 2; ++ks) {
            bf16x8 bfv = *(const bf16x8*)(const void*)(&Vtl[cur][ks * 512 + lm * 32 + lq * 8]);
#pragma unroll
            for (int mt = 0; mt < 2; ++mt) {
                bf16x8 af = *(const bf16x8*)(const void*)(
                    &Ktl[cur][ks * 4096 + (32 * wave + 16 * mt + lm) * 32 + lq * 8]);
                uacc[mt] = __builtin_amdgcn_mfma_f32_16x16x32_bf16(af, bfv, uacc[mt], 0, 0, 0);
            }
        }
        // Y = Qs @ M[cur] : wave j-strip [16*wave, +16)
        f32x4 yacc = {};
#pragma unroll
        for (int ks = 0; ks < 4; ++ks) {
            bf16x8 af = *(const bf16x8*)(const void*)(
                &Qsl[cur][ks * 2048 + (16 * wave + lm) * 32 + lq * 8]);
            float4 m0 = *(const float4*)(const void*)(&Ml[cur][lm * 132 + ks * 32 + lq * 8]);
            float4 m1 = *(const float4*)(const void*)(&Ml[cur][lm * 132 + ks * 32 + lq * 8 + 4]);
            __align__(16) unsigned short tmp[8];
            tmp[0] = f2us(m0.x); tmp[1] = f2us(m0.y); tmp[2] = f2us(m0.z); tmp[3] = f2us(m0.w);
            tmp[4] = f2us(m1.x); tmp[5] = f2us(m1.y); tmp[6] = f2us(m1.z); tmp[7] = f2us(m1.w);
            bf16x8 bfm = *(const bf16x8*)tmp;
            yacc = __builtin_amdgcn_mfma_f32_16x16x32_bf16(af, bfm, yacc, 0, 0, 0);
        }
        // yb += o * Y_inter
#pragma unroll
        for (int r = 0; r < 4; ++r)
            yb[yidx[r]] = f2us(bf2f(prevy[r]) + osv[r] * yacc[r]);
        // VALU-stage V for chunk c+1 into nxt buffer
        if (c + 1 < NCH) {
            const int t0n = t0 + CCH;
#pragma unroll
            for (int r = 0; r < 4; ++r) {
                int lin = r * 256 + tid;
                int s = lin >> 4, e = lin & 15;
                float val = bf2f(vg[((size_t)(b * LQ + t0n + s)) * HID + hh * DHEAD + e0 + e]);
                Vtl[nxt][(s >> 5) * 512 + e * 32 + (s & 31)] = f2us(val);
            }
        }
        // M[nxt] = cd * M[cur] + U  (write other buffer -> no barrier needed)
#pragma unroll
        for (int mt = 0; mt < 2; ++mt)
#pragma unroll
            for (int r = 0; r < 4; ++r) {
                int d = 32 * wave + 16 * mt + lq * 4 + r;
                Ml[nxt][lm * 132 + d] = cd * Ml[cur][lm * 132 + d] + uacc[mt][r];
            }
    }
}

// ---------------------------------------------------------------------------
extern "C" void kernel_launch(void* const* d_in, const int* in_sizes, int n_in,
                              void* d_out, int out_size, void* d_ws, size_t ws_size,
                              hipStream_t stream) {
    const void* x      = d_in[0];
    const void* norm_w = d_in[1];
    const void* Wq     = d_in[2];
    const void* Wk     = d_in[3];
    const void* Wv     = d_in[4];
    const void* Wbeta  = d_in[5];
    const void* bbeta  = d_in[6];
    const void* Wig    = d_in[7];
    const void* big    = d_in[8];
    const void* Wog    = d_in[9];
    const void* bog    = d_in[10];
    const void* Wout   = d_in[11];
    const void* bout   = d_in[12];

    char* ws = (char*)d_ws;
    const size_t KB = 1024, MB = 1024 * 1024;
    int*   flag    = (int*)(ws + 0);
    float* bbeta_c = (float*)(ws + 1 * KB);
    float* big_c   = (float*)(ws + 1 * KB + 32);
    float* bog_c   = (float*)(ws + 1 * KB + 64);
    float* bout_c  = (float*)(ws + 4 * KB);
    float* cdecG   = (float*)(ws + 16 * KB);            // 8 KiB
    unsigned short* Wbeta_c = (unsigned short*)(ws + 64 * KB);
    unsigned short* Wig_c   = (unsigned short*)(ws + 96 * KB);
    unsigned short* Wog_c   = (unsigned short*)(ws + 128 * KB);
    float* fT   = (float*)(ws + 1 * MB);
    float* gT   = (float*)(ws + 1 * MB + 512 * KB);
    float* oT   = (float*)(ws + 2 * MB);
    float* cosT = (float*)(ws + 2 * MB + 512 * KB);
    float* sinT = (float*)(ws + 3 * MB + 512 * KB);
    unsigned short* Wq_c   = (unsigned short*)(ws + 5 * MB);
    unsigned short* Wk_c   = (unsigned short*)(ws + 7 * MB);
    unsigned short* Wv_c   = (unsigned short*)(ws + 9 * MB);
    unsigned short* Wout_c = (unsigned short*)(ws + 11 * MB);
    __hip_bfloat16* h  = (__hip_bfloat16*)(ws + 16 * MB);   // 32 MiB; dead after QKV gemm
    unsigned short* ktg = (unsigned short*)(ws + 16 * MB);  // aliases h (32 MiB)
    unsigned short* qb = (unsigned short*)(ws + 48 * MB);
    unsigned short* kb = (unsigned short*)(ws + 80 * MB);
    unsigned short* vb = (unsigned short*)(ws + 112 * MB);
    __hip_bfloat16* yb = (__hip_bfloat16*)(ws + 144 * MB);

    detect_kernel<<<1, 64, 0, stream>>>(x, flag);
    cvt_w4_kernel<<<dim3(1024, 5), 256, 0, stream>>>(Wq, Wk, Wv, Wout,
                                                     Wq_c, Wk_c, Wv_c, Wout_c,
                                                     cosT, sinT, flag);
    cvt_small_kernel<<<101, 256, 0, stream>>>(Wbeta, Wig, Wog, bbeta, big, bog, bout,
                                              Wbeta_c, Wig_c, Wog_c,
                                              bbeta_c, big_c, bog_c, bout_c, flag);
    rmsnorm_gates_kernel<<<MROWS, 256, 0, stream>>>(
        x, norm_w, h, flag,
        (const __hip_bfloat16*)Wbeta_c, bbeta_c,
        (const __hip_bfloat16*)Wig_c, big_c,
        (const __hip_bfloat16*)Wog_c, bog_c, fT, gT, oT);

    gemm_qkv<<<dim3(MROWS / 256, 12), 512, 0, stream>>>(h, Wq_c, Wk_c, Wv_c, qb, kb, vb);

    intra_kernel<<<dim3(NCH, 32), 256, 0, stream>>>(qb, kb, vb, fT, gT, oT, cosT, sinT,
                                                    (__hip_bfloat16*)yb, ktg, cdecG);
    inter_kernel<<<dim3(32, 8), 256, 0, stream>>>(qb, ktg, vb, oT, cdecG,
                                                  (unsigned short*)yb);

    gemm_bt<<<dim3(MROWS / 256, HID / 256), 512, 0, stream>>>(
        (const __hip_bfloat16*)yb, (const __hip_bfloat16*)Wout_c, bout_c, d_out, flag);
}

// Round 5
// 507.484 us; speedup vs baseline: 1.0694x; 1.0539x over previous
//
#include <hip/hip_runtime.h>
#include <hip/hip_bf16.h>

#define BQ 4
#define LQ 4096
#define HID 1024
#define NHEAD 8
#define DHEAD 128
#define MROWS (BQ * LQ) /* 16384 */
#define CCH 64          /* chunk length */
#define NCH (LQ / CCH)  /* 64 chunks */
#define GNT 16          /* K-tiles of 64 in the 256^2 GEMMs */

typedef __bf16 bf16x8 __attribute__((ext_vector_type(8)));
typedef float f32x4 __attribute__((ext_vector_type(4)));

__device__ __forceinline__ float bf2f(unsigned short u) {
    return __uint_as_float(((unsigned int)u) << 16);
}
__device__ __forceinline__ unsigned short f2us(float f) {
    __hip_bfloat16 b = __float2bfloat16(f);
    return *reinterpret_cast<unsigned short*>(&b);
}
__device__ __forceinline__ float loadAny(const void* p, size_t i, bool isf) {
    return isf ? ((const float*)p)[i] : bf2f(((const unsigned short*)p)[i]);
}

// ---------------------------------------------------------------------------
// Dtype probe: flag=1 -> inputs are f32; flag=0 -> bf16.
// ---------------------------------------------------------------------------
__global__ void detect_kernel(const void* x, int* flag) {
    const unsigned short* u = (const unsigned short*)x;
    int t = threadIdx.x;  // 64 threads
    int cnt = 0;
#pragma unroll
    for (int s = 0; s < 64; ++s) {
        unsigned short v = u[2 * (t * 64 + s)];
        int e = (v >> 7) & 0xFF;
        cnt += (e >= 0x8A || (e != 0 && e <= 0x6E)) ? 1 : 0;
    }
#pragma unroll
    for (int m = 1; m < 64; m <<= 1) cnt += __shfl_xor(cnt, m);
    if (t == 0) *flag = (cnt > 1024) ? 1 : 0;
}

// ---------------------------------------------------------------------------
// Convert the four 1024x1024 weights to bf16; blockIdx.y==4 builds RoPE tables.
// ---------------------------------------------------------------------------
__global__ __launch_bounds__(256) void cvt_w4_kernel(
    const void* Wq, const void* Wk, const void* Wv, const void* Wout,
    unsigned short* dq, unsigned short* dk, unsigned short* dv, unsigned short* dout,
    float* __restrict__ cosT, float* __restrict__ sinT,
    const int* flagp) {
    if (blockIdx.y == 4) {
        int idx = blockIdx.x * 256 + threadIdx.x;  // 0..262143 = 4096*64
        int l = idx >> 6, i = idx & 63;
        float invf = powf(10000.0f, -(float)i * (1.0f / 64.0f));
        float fr = (float)l * invf;
        cosT[idx] = cosf(fr);
        sinT[idx] = sinf(fr);
        return;
    }
    const bool isf = (*flagp != 0);
    const void* s;
    unsigned short* d;
    switch (blockIdx.y) {
        case 0: s = Wq; d = dq; break;
        case 1: s = Wk; d = dk; break;
        case 2: s = Wv; d = dv; break;
        default: s = Wout; d = dout; break;
    }
    size_t i = ((size_t)blockIdx.x * 256 + threadIdx.x) * 4;
#pragma unroll
    for (int r = 0; r < 4; ++r) d[i + r] = f2us(loadAny(s, i + r, isf));
}

// ---------------------------------------------------------------------------
// Convert gate weights (3 x 8x1024 -> bf16) and biases (-> f32).
// ---------------------------------------------------------------------------
__global__ __launch_bounds__(256) void cvt_small_kernel(
    const void* Wbeta, const void* Wig, const void* Wog,
    const void* bbeta, const void* big, const void* bog, const void* bout,
    unsigned short* dWb, unsigned short* dWi, unsigned short* dWo,
    float* dbb, float* dbi, float* dbo, float* dbout,
    const int* flagp) {
    const bool isf = (*flagp != 0);
    int gid = blockIdx.x * 256 + threadIdx.x;
    if (gid < 24576) {
        int seg = gid >> 13, off = gid & 8191;
        const void* s = (seg == 0) ? Wbeta : (seg == 1) ? Wig : Wog;
        unsigned short* d = (seg == 0) ? dWb : (seg == 1) ? dWi : dWo;
        d[off] = f2us(loadAny(s, off, isf));
    } else {
        int j = gid - 24576;
        if (j < 8) dbb[j] = loadAny(bbeta, j, isf);
        else if (j < 16) dbi[j - 8] = loadAny(big, j - 8, isf);
        else if (j < 24) dbo[j - 16] = loadAny(bog, j - 16, isf);
        else if (j < 24 + 1024) dbout[j - 24] = loadAny(bout, j - 24, isf);
    }
}

// ---------------------------------------------------------------------------
// Fused RMSNorm + gates: h = x*rsqrt(mean(x^2)+1e-6)*w (bf16 out), and the
// 24 sigmoid gates computed from the normalized row held in registers.
// ---------------------------------------------------------------------------
__global__ __launch_bounds__(256) void rmsnorm_gates_kernel(
    const void* __restrict__ xin, const void* __restrict__ win,
    __hip_bfloat16* __restrict__ h, const int* __restrict__ flagp,
    const __hip_bfloat16* __restrict__ Wbeta, const float* __restrict__ bbeta,
    const __hip_bfloat16* __restrict__ Wig, const float* __restrict__ big,
    const __hip_bfloat16* __restrict__ Wog, const float* __restrict__ bog,
    float* __restrict__ fT, float* __restrict__ gT, float* __restrict__ oT) {
    const bool isf = (*flagp != 0);
    const int row = blockIdx.x;
    const int tid = threadIdx.x;
    const int lane = tid & 63, wave = tid >> 6;
    const int b = row >> 12, l = row & (LQ - 1);
    const size_t base = (size_t)row * HID;
    float x0, x1, x2, x3;
    if (isf) {
        float4 u = ((const float4*)((const float*)xin + base))[tid];
        x0 = u.x; x1 = u.y; x2 = u.z; x3 = u.w;
    } else {
        ushort4 u = ((const ushort4*)((const unsigned short*)xin + base))[tid];
        x0 = bf2f(u.x); x1 = bf2f(u.y); x2 = bf2f(u.z); x3 = bf2f(u.w);
    }
    float ss = x0 * x0 + x1 * x1 + x2 * x2 + x3 * x3;
#pragma unroll
    for (int m = 1; m < 64; m <<= 1) ss += __shfl_xor(ss, m);
    __shared__ float wsum[4];
    if (lane == 0) wsum[wave] = ss;
    __syncthreads();
    float tot = wsum[0] + wsum[1] + wsum[2] + wsum[3];
    float inv = rsqrtf(tot * (1.0f / HID) + 1e-6f);
    float w0, w1, w2, w3;
    if (isf) {
        float4 u = ((const float4*)win)[tid];
        w0 = u.x; w1 = u.y; w2 = u.z; w3 = u.w;
    } else {
        ushort4 u = ((const ushort4*)win)[tid];
        w0 = bf2f(u.x); w1 = bf2f(u.y); w2 = bf2f(u.z); w3 = bf2f(u.w);
    }
    float h0 = x0 * inv * w0, h1 = x1 * inv * w1, h2 = x2 * inv * w2, h3 = x3 * inv * w3;
    __hip_bfloat16* ho = h + base + tid * 4;
    ho[0] = __float2bfloat16(h0);
    ho[1] = __float2bfloat16(h1);
    ho[2] = __float2bfloat16(h2);
    ho[3] = __float2bfloat16(h3);
    // gates from register h
    float p[24];
#pragma unroll
    for (int g = 0; g < 24; ++g) {
        const __hip_bfloat16* wr = (g < 8) ? (Wbeta + g * HID)
                                 : (g < 16) ? (Wig + (g - 8) * HID)
                                            : (Wog + (g - 16) * HID);
        const unsigned short* wp = (const unsigned short*)wr + tid * 4;
        ushort4 wu = *(const ushort4*)wp;
        p[g] = h0 * bf2f(wu.x) + h1 * bf2f(wu.y) + h2 * bf2f(wu.z) + h3 * bf2f(wu.w);
    }
#pragma unroll
    for (int m = 1; m < 64; m <<= 1) {
#pragma unroll
        for (int g = 0; g < 24; ++g) p[g] += __shfl_xor(p[g], m);
    }
    __shared__ float part[4][24];
    if (lane == 0) {
#pragma unroll
        for (int g = 0; g < 24; ++g) part[wave][g] = p[g];
    }
    __syncthreads();
    if (tid < 24) {
        int g = tid;
        float s = part[0][g] + part[1][g] + part[2][g] + part[3][g];
        float bb = (g < 8) ? bbeta[g] : (g < 16) ? big[g - 8] : bog[g - 16];
        s += bb;
        s = 1.0f / (1.0f + expf(-s));
        int hh = (g < 8) ? g : (g < 16) ? g - 8 : g - 16;
        float* dst = (g < 8) ? fT : (g < 16) ? gT : oT;
        dst[((size_t)(b * NHEAD + hh)) * LQ + l] = s;
    }
}

// ---------------------------------------------------------------------------
// 256x256 (BK=64) 8-wave 4-phase GEMM core with REGISTER-HELD fragments.
//
// Round-3 post-mortem: quadrant phasing re-read A and B twice per K-tile
// (48 ds_read_b128 for 64 MFMA) -> LDS-pipe-bound (MfmaUtil 31%, conflicts
// already 0).  This version holds fragments in registers (m201's "4 or 8
// reads per phase" pattern): B (all 8 frags, 32 VGPR) lives the whole
// K-tile; A (8 frags, 32 VGPR) lives across its two phases.  24 unique
// reads per K-tile; ph3 issues no ds_reads.
//
// Sync skeleton (race-screened in round 3, unchanged semantics):
//   * staging ONLY into the next buffer (tile t stages t+1 into buf t^1,
//     whose readers finished at tile t-1's closing barrier);
//   * stage issue order A0,B0@ph0  B1@ph1  A1@ph2  (one phase of slack
//     before the single vmcnt(0) at ph3-close drains them);
//   * ONE vmcnt(0) per K-tile (ph3-close) -- depth-1 pipeline, so only
//     tile t+1's 8 stage-loads are in flight; nothing else gets drained;
//   * every barrier / waitcnt sealed with sched_barrier(0) on both sides;
//     lgkmcnt(0)+seal before each MFMA cluster (rule #18).
//   * T2 granule-XOR swizzle: 16B granule g of row r lives at g^(r&7);
//     linear LDS dest, pre-swizzled global source, XOR'd ds_read address.
//   * T5 setprio(1) around each 16-MFMA cluster.
// ---------------------------------------------------------------------------
__device__ __forceinline__ void g256_stage_half(const unsigned short* __restrict__ src,
                                                unsigned short* lds, int tid) {
#pragma unroll
    for (int l = 0; l < 2; ++l) {
        int L = l * 512 + tid;          // 1024 granules = 128 rows x 8
        int r = L >> 3, g = L & 7;
        int gs = g ^ (r & 7);           // pre-swizzled global source
        __builtin_amdgcn_global_load_lds(
            (const __attribute__((address_space(1))) void*)(src + (size_t)r * HID + gs * 8),
            (__attribute__((address_space(3))) void*)(lds + L * 8), 16, 0, 0);
    }
}

#define G256_SEAL() __builtin_amdgcn_sched_barrier(0)
#define G256_BARRIER()            \
    do {                          \
        G256_SEAL();              \
        __builtin_amdgcn_s_barrier(); \
        G256_SEAL();              \
    } while (0)
#define G256_LGKM0()                                        \
    do {                                                    \
        asm volatile("s_waitcnt lgkmcnt(0)" ::: "memory");  \
        G256_SEAL();                                        \
    } while (0)

__device__ __forceinline__ void g256_read_A(const unsigned short* Ac, int mq,
                                            int wr, int lm, int lq, bf16x8 (&bA)[4][2]) {
#pragma unroll
    for (int i = 0; i < 4; ++i) {
        const int row = mq * 128 + wr * 64 + i * 16 + lm;
#pragma unroll
        for (int kk = 0; kk < 2; ++kk) {
            const int gsw = (kk * 4 + lq) ^ (lm & 7);
            bA[i][kk] = *(const bf16x8*)(const void*)(Ac + row * 64 + gsw * 8);
        }
    }
}
__device__ __forceinline__ void g256_read_B(const unsigned short* Bc, int nq,
                                            int wc, int lm, int lq, bf16x8 (&bB)[2][2]) {
#pragma unroll
    for (int j = 0; j < 2; ++j) {
        const int row = nq * 128 + wc * 32 + j * 16 + lm;
#pragma unroll
        for (int kk = 0; kk < 2; ++kk) {
            const int gsw = (kk * 4 + lq) ^ (lm & 7);
            bB[j][kk] = *(const bf16x8*)(const void*)(Bc + row * 64 + gsw * 8);
        }
    }
}
__device__ __forceinline__ void g256_mfma(int mq, int nq, const bf16x8 (&bA)[4][2],
                                          const bf16x8 (&bB)[2][2], f32x4 (&acc)[8][4]) {
    __builtin_amdgcn_s_setprio(1);
#pragma unroll
    for (int i = 0; i < 4; ++i)
#pragma unroll
        for (int j = 0; j < 2; ++j)
#pragma unroll
            for (int kk = 0; kk < 2; ++kk)
                acc[mq * 4 + i][nq * 2 + j] = __builtin_amdgcn_mfma_f32_16x16x32_bf16(
                    bA[i][kk], bB[j][kk], acc[mq * 4 + i][nq * 2 + j], 0, 0, 0);
    __builtin_amdgcn_s_setprio(0);
}

__device__ __forceinline__ void g256_core(const unsigned short* __restrict__ A,
                                          const unsigned short* __restrict__ W,
                                          unsigned short* As, unsigned short* Bs,
                                          int m0, int tid, f32x4 (&acc)[8][4]) {
    const int lane = tid & 63, wid = tid >> 6;
    const int wr = wid >> 2, wc = wid & 3;
    const int lm = lane & 15, lq = lane >> 4;
    // prologue: tile0 all 4 halves -> buf0, full drain, barrier.
    g256_stage_half(A + (size_t)m0 * HID, As, tid);                  // A0
    g256_stage_half(W, Bs, tid);                                     // B0
    g256_stage_half(W + (size_t)128 * HID, Bs + 8192, tid);          // B1
    g256_stage_half(A + (size_t)(m0 + 128) * HID, As + 8192, tid);   // A1
    G256_SEAL();
    asm volatile("s_waitcnt vmcnt(0)" ::: "memory");
    G256_BARRIER();
    for (int t = 0; t < GNT; ++t) {
        unsigned short* Ac = As + (t & 1) * 16384;
        unsigned short* Bc = Bs + (t & 1) * 16384;
        unsigned short* An = As + ((t & 1) ^ 1) * 16384;
        unsigned short* Bn = Bs + ((t & 1) ^ 1) * 16384;
        const int kn = (t + 1) * 64;
        const bool pf = (t + 1 < GNT);
        bf16x8 bA[4][2], bB0[2][2], bB1[2][2];
        // ---- ph0: read A(mq0)+B(nq0); stage (t+1).A0,(t+1).B0 ----
        g256_read_A(Ac, 0, wr, lm, lq, bA);
        g256_read_B(Bc, 0, wc, lm, lq, bB0);
        if (pf) {
            g256_stage_half(A + (size_t)m0 * HID + kn, An, tid);
            g256_stage_half(W + kn, Bn, tid);
        }
        G256_BARRIER();
        G256_LGKM0();
        g256_mfma(0, 0, bA, bB0, acc);
        G256_BARRIER();
        // ---- ph1: read B(nq1); stage (t+1).B1 ----
        g256_read_B(Bc, 1, wc, lm, lq, bB1);
        if (pf) g256_stage_half(W + (size_t)128 * HID + kn, Bn + 8192, tid);
        G256_BARRIER();
        G256_LGKM0();
        g256_mfma(0, 1, bA, bB1, acc);
        G256_BARRIER();
        // ---- ph2: read A(mq1); stage (t+1).A1 ----
        g256_read_A(Ac, 1, wr, lm, lq, bA);
        if (pf) g256_stage_half(A + (size_t)(m0 + 128) * HID + kn, An + 8192, tid);
        G256_BARRIER();
        G256_LGKM0();
        g256_mfma(1, 0, bA, bB0, acc);
        G256_BARRIER();
        // ---- ph3: no ds_reads, no staging; drain tile t+1's stages ----
        g256_mfma(1, 1, bA, bB1, acc);
        G256_SEAL();
        if (pf) asm volatile("s_waitcnt vmcnt(0)" ::: "memory");
        G256_BARRIER();
    }
}

// ---------------------------------------------------------------------------
// Merged QKV GEMM on the 256^2 core: blockIdx.y in [0,12) -> weight y>>2,
// column block (y&3)*256.
// ---------------------------------------------------------------------------
__global__ __launch_bounds__(512) void gemm_qkv(const __hip_bfloat16* __restrict__ A,
                                                const unsigned short* __restrict__ Wqc,
                                                const unsigned short* __restrict__ Wkc,
                                                const unsigned short* __restrict__ Wvc,
                                                unsigned short* __restrict__ qb,
                                                unsigned short* __restrict__ kb,
                                                unsigned short* __restrict__ vb) {
    __shared__ __align__(16) unsigned short As[2 * 16384];
    __shared__ __align__(16) unsigned short Bs[2 * 16384];
    const int nblk = blockIdx.y;
    const int sel = nblk >> 2;
    const int nl0 = (nblk & 3) * 256;
    const unsigned short* W = (sel == 0 ? Wqc : sel == 1 ? Wkc : Wvc) + (size_t)nl0 * HID;
    unsigned short* C = (sel == 0) ? qb : (sel == 1) ? kb : vb;
    const int tid = threadIdx.x;
    const int lane = tid & 63, wid = tid >> 6;
    const int wr = wid >> 2, wc = wid & 3;
    const int lm = lane & 15, lq = lane >> 4;
    const int m0 = blockIdx.x * 256;
    f32x4 acc[8][4] = {};
    g256_core((const unsigned short*)A, W, As, Bs, m0, tid, acc);
#pragma unroll
    for (int mq = 0; mq < 2; ++mq)
#pragma unroll
        for (int i = 0; i < 4; ++i)
#pragma unroll
            for (int nq = 0; nq < 2; ++nq)
#pragma unroll
                for (int j = 0; j < 2; ++j) {
                    const int col = nl0 + nq * 128 + wc * 32 + j * 16 + lm;
#pragma unroll
                    for (int r = 0; r < 4; ++r) {
                        const int rowg = m0 + mq * 128 + wr * 64 + i * 16 + lq * 4 + r;
                        C[(size_t)rowg * HID + col] = f2us(acc[mq * 4 + i][nq * 2 + j][r]);
                    }
                }
}

// ---------------------------------------------------------------------------
// Final GEMM on the 256^2 core: C = A W^T + bias; C f32 when (*flagp).
// ---------------------------------------------------------------------------
__global__ __launch_bounds__(512) void gemm_bt(const __hip_bfloat16* __restrict__ A,
                                               const __hip_bfloat16* __restrict__ W,
                                               const float* __restrict__ bias,
                                               void* __restrict__ C,
                                               const int* __restrict__ flagp) {
    __shared__ __align__(16) unsigned short As[2 * 16384];
    __shared__ __align__(16) unsigned short Bs[2 * 16384];
    const bool f32out = (*flagp != 0);
    const int tid = threadIdx.x;
    const int lane = tid & 63, wid = tid >> 6;
    const int wr = wid >> 2, wc = wid & 3;
    const int lm = lane & 15, lq = lane >> 4;
    const int m0 = blockIdx.x * 256;
    const int nl0 = blockIdx.y * 256;
    f32x4 acc[8][4] = {};
    g256_core((const unsigned short*)A, (const unsigned short*)W + (size_t)nl0 * HID,
              As, Bs, m0, tid, acc);
#pragma unroll
    for (int mq = 0; mq < 2; ++mq)
#pragma unroll
        for (int i = 0; i < 4; ++i)
#pragma unroll
            for (int nq = 0; nq < 2; ++nq)
#pragma unroll
                for (int j = 0; j < 2; ++j) {
                    const int col = nl0 + nq * 128 + wc * 32 + j * 16 + lm;
                    const float bv = bias[col];
#pragma unroll
                    for (int r = 0; r < 4; ++r) {
                        const int rowg = m0 + mq * 128 + wr * 64 + i * 16 + lq * 4 + r;
                        const size_t idx = (size_t)rowg * HID + col;
                        const float val = acc[mq * 4 + i][nq * 2 + j][r] + bv;
                        if (f32out) ((float*)C)[idx] = val;
                        else ((__hip_bfloat16*)C)[idx] = __float2bfloat16(val);
                    }
                }
}

// ---------------------------------------------------------------------------
// INTRA kernel + prep. Q is never staged to LDS: each lane builds its MFMA
// A-fragment of rope(q) in registers (pair i/i+64 lives in the same thread)
// and writes scaled qb back from the same registers. LDS = Kr+Vt+Sp ~46 KB
// -> 3 blocks/CU (was 2).
// ---------------------------------------------------------------------------
__global__ __launch_bounds__(256) void intra_kernel(
    unsigned short* __restrict__ qg, const unsigned short* __restrict__ kg,
    const unsigned short* __restrict__ vg,
    const float* __restrict__ fT, const float* __restrict__ gT, const float* __restrict__ oT,
    const float* __restrict__ cosT, const float* __restrict__ sinT,
    __hip_bfloat16* __restrict__ yb,
    unsigned short* __restrict__ ktg, float* __restrict__ cdecG) {
    const int chunk = blockIdx.x;        // 0..63
    const int bh = blockIdx.y;           // 0..31
    const int b = bh >> 3, hh = bh & 7;
    const int t0 = chunk * CCH;
    const int tid = threadIdx.x;
    const int lane = tid & 63, wave = tid >> 6;
    const int lm = lane & 15, lq = lane >> 4;
    __shared__ unsigned short Kr[64 * 136];
    __shared__ unsigned short Vt[128 * 72];
    __shared__ unsigned short Sp[64 * 72];
    __shared__ float Lp[64], aS[64], osh[64], w2s[64], qscs[64];

    // phase 0: gates + decay prefix (wave 0)
    if (tid < 64) {
        float f = fT[(size_t)bh * LQ + t0 + tid];
        float g = gT[(size_t)bh * LQ + t0 + tid];
        osh[tid] = oT[(size_t)bh * LQ + t0 + tid];
        float lf = __logf(f);
#pragma unroll
        for (int off = 1; off < 64; off <<= 1) {
            float v = __shfl_up(lf, off);
            if (lane >= off) lf += v;
        }
        float tot = __shfl(lf, 63);
        Lp[tid] = lf;
        aS[tid] = g * 0.08838834764831845f;  // g / sqrt(128)
        w2s[tid] = __expf(tot - lf) * (g * 0.08838834764831845f);
        qscs[tid] = __expf(lf);
        if (tid == 63) cdecG[bh * NCH + chunk] = __expf(lf);
    }
    __syncthreads();  // B0

    // phase 1a: Q fragments in registers + scaled write-back.
    // Lane owns row (16*wave+lm), k-cols ks*32+lq*8+[0,8) for ks=0..3.
    bf16x8 af[4];
    {
        const int jr = 16 * wave + lm;
        const int gt = t0 + jr;
        const size_t qbase = ((size_t)(b * LQ + gt)) * HID + hh * DHEAD;
        uint4 qraw[4];
#pragma unroll
        for (int ks = 0; ks < 4; ++ks)
            qraw[ks] = *(const uint4*)(qg + qbase + ks * 32 + lq * 8);
        const unsigned short* q0 = (const unsigned short*)&qraw[0];
        const unsigned short* q1 = (const unsigned short*)&qraw[1];
        const unsigned short* q2 = (const unsigned short*)&qraw[2];
        const unsigned short* q3 = (const unsigned short*)&qraw[3];
        const float sc = qscs[jr];
        __align__(16) unsigned short fr[4][8];
        __align__(16) unsigned short qo[4][8];
#pragma unroll
        for (int u = 0; u < 8; ++u) {
            int i = lq * 8 + u;          // pair (i, i+64) for ks 0<->2
            int i2 = 32 + lq * 8 + u;    // pair for ks 1<->3
            float c0 = cosT[gt * 64 + i], s0 = sinT[gt * 64 + i];
            float c1 = cosT[gt * 64 + i2], s1 = sinT[gt * 64 + i2];
            float a = bf2f(q0[u]), bq = bf2f(q2[u]);
            float rc = a * c0 - bq * s0, rs = a * s0 + bq * c0;
            fr[0][u] = f2us(rc); fr[2][u] = f2us(rs);
            qo[0][u] = f2us(rc * sc); qo[2][u] = f2us(rs * sc);
            float a1 = bf2f(q1[u]), bq1 = bf2f(q3[u]);
            float rc1 = a1 * c1 - bq1 * s1, rs1 = a1 * s1 + bq1 * c1;
            fr[1][u] = f2us(rc1); fr[3][u] = f2us(rs1);
            qo[1][u] = f2us(rc1 * sc); qo[3][u] = f2us(rs1 * sc);
        }
#pragma unroll
        for (int ks = 0; ks < 4; ++ks) {
            af[ks] = *(const bf16x8*)fr[ks];
            *(uint4*)(qg + qbase + ks * 32 + lq * 8) = *(const uint4*)qo[ks];
        }
    }
    // phase 1b: rope-stage K into LDS
#pragma unroll
    for (int r = 0; r < 16; ++r) {
        int pid = r * 256 + tid;
        int t = pid >> 6, i = pid & 63;
        int gt = t0 + t;
        size_t gidx = ((size_t)(b * LQ + gt)) * HID + hh * DHEAD + i;
        float c = cosT[gt * 64 + i], s = sinT[gt * 64 + i];
        float k1 = bf2f(kg[gidx]), k2 = bf2f(kg[gidx + 64]);
        Kr[t * 136 + i] = f2us(k1 * c - k2 * s);
        Kr[t * 136 + i + 64] = f2us(k1 * s + k2 * c);
    }
    // stage V transposed: Vt[e][s]
#pragma unroll
    for (int r = 0; r < 32; ++r) {
        int lin = r * 256 + tid;
        int sI = lin >> 7, e = lin & 127;
        float val = bf2f(vg[((size_t)(b * LQ + t0 + sI)) * HID + hh * DHEAD + e]);
        Vt[e * 72 + sI] = f2us(val);
    }
    __syncthreads();  // B1

    // S = Q K^T (64x64, K=128); wave j-strip [16*wave,+16), Q from registers
    f32x4 sacc[4] = {};
#pragma unroll
    for (int ks = 0; ks < 4; ++ks) {
#pragma unroll
        for (int nt = 0; nt < 4; ++nt) {
            bf16x8 bf = *(const bf16x8*)(const void*)(Kr + (nt * 16 + lm) * 136 + ks * 32 + lq * 8);
            sacc[nt] = __builtin_amdgcn_mfma_f32_16x16x32_bf16(af[ks], bf, sacc[nt], 0, 0, 0);
        }
    }
    // mask + decay/gate scale, store S' bf16 [j][s]
#pragma unroll
    for (int nt = 0; nt < 4; ++nt) {
#pragma unroll
        for (int r = 0; r < 4; ++r) {
            int j = 16 * wave + lq * 4 + r;
            int s = nt * 16 + lm;
            float v = 0.0f;
            if (j >= s) v = sacc[nt][r] * __expf(Lp[j] - Lp[s]) * aS[s];
            Sp[j * 72 + s] = f2us(v);
        }
    }
    // PREP: KtG[ks][d][32] = w2_s * Kr[s][d]
    {
        unsigned short* krec = ktg + ((size_t)(bh * NCH + chunk)) * 8192;
#pragma unroll
        for (int r = 0; r < 2; ++r) {
            int lin16 = r * 256 + tid;
            int ks = lin16 >> 8;
            int d = (lin16 & 255) >> 1;
            int cc0 = (lin16 & 1) * 16;
            __align__(16) unsigned short out[16];
#pragma unroll
            for (int u = 0; u < 16; ++u) {
                int s = ks * 32 + cc0 + u;
                out[u] = f2us(w2s[s] * bf2f(Kr[s * 136 + d]));
            }
            uint4* dst = (uint4*)(krec + (size_t)lin16 * 16);
            dst[0] = *(const uint4*)(out);
            dst[1] = *(const uint4*)(out + 8);
        }
    }
    __syncthreads();  // B2

    // Y_intra = S' V  (64x128, K=64)
    f32x4 ya[8] = {};
#pragma unroll
    for (int ks = 0; ks < 2; ++ks) {
        bf16x8 afs = *(const bf16x8*)(const void*)(Sp + (16 * wave + lm) * 72 + ks * 32 + lq * 8);
#pragma unroll
        for (int nt = 0; nt < 8; ++nt) {
            bf16x8 bf = *(const bf16x8*)(const void*)(Vt + (nt * 16 + lm) * 72 + ks * 32 + lq * 8);
            ya[nt] = __builtin_amdgcn_mfma_f32_16x16x32_bf16(afs, bf, ya[nt], 0, 0, 0);
        }
    }
#pragma unroll
    for (int nt = 0; nt < 8; ++nt) {
#pragma unroll
        for (int r = 0; r < 4; ++r) {
            int j = 16 * wave + lq * 4 + r;
            int e = nt * 16 + lm;
            size_t row = (size_t)(b * LQ + t0 + j);
            yb[row * HID + hh * DHEAD + e] = __float2bfloat16(osh[j] * ya[nt][r]);
        }
    }
}

// ---------------------------------------------------------------------------
// INTER kernel: ONE barrier per chunk. State M double-buffered in LDS (read
// M[c&1], write M[(c+1)&1]) so no second barrier is needed; Q/K DMA for c+1
// issued AFTER the top barrier so it stays in flight through chunk c's
// compute and is drained by the NEXT barrier (true prefetch overlap).
// yb RMW values prefetched right after the barrier to hide their latency.
// ---------------------------------------------------------------------------
__global__ __launch_bounds__(256) void inter_kernel(
    const unsigned short* __restrict__ qs,   // exp(Lp_j)*rope(q), [row][128]
    const unsigned short* __restrict__ ktg,  // [bh][chunk][ks][d][32]
    const unsigned short* __restrict__ vg,
    const float* __restrict__ oT, const float* __restrict__ cdecG,
    unsigned short* __restrict__ yb) {
    const int bh = blockIdx.x;       // 0..31
    const int esplit = blockIdx.y;   // 0..7
    const int e0 = esplit * 16;
    const int b = bh >> 3, hh = bh & 7;
    const int tid = threadIdx.x;
    const int lane = tid & 63, wave = tid >> 6;
    const int lm = lane & 15, lq = lane >> 4;
    __shared__ __align__(16) unsigned short Qsl[2][8192];  // [ks(4)][j(64)][32]
    __shared__ __align__(16) unsigned short Ktl[2][8192];  // [ks(2)][d(128)][32]
    __shared__ __align__(16) unsigned short Vtl[2][1024];  // [ks(2)][e(16)][32]
    __shared__ __align__(16) float Ml[2][16 * 132];        // M^T [e][d], stride 132

    for (int i = tid; i < 16 * 132; i += 256) Ml[0][i] = 0.0f;

    const int jrow = tid >> 2;
    const int qcol = (tid & 3) * 8;
    // prologue: DMA chunk 0 into buf 0, VALU-stage V0
    {
        const unsigned short* qrow =
            qs + ((size_t)(b * LQ + jrow)) * HID + hh * DHEAD + qcol;
#pragma unroll
        for (int ks = 0; ks < 4; ++ks)
            __builtin_amdgcn_global_load_lds(
                (const __attribute__((address_space(1))) void*)(qrow + ks * 32),
                (__attribute__((address_space(3))) void*)(&Qsl[0][ks * 2048 + tid * 8]),
                16, 0, 0);
        const unsigned short* kbase = ktg + ((size_t)(bh * NCH)) * 8192 + tid * 8;
#pragma unroll
        for (int i = 0; i < 4; ++i)
            __builtin_amdgcn_global_load_lds(
                (const __attribute__((address_space(1))) void*)(kbase + i * 2048),
                (__attribute__((address_space(3))) void*)(&Ktl[0][i * 2048 + tid * 8]),
                16, 0, 0);
#pragma unroll
        for (int r = 0; r < 4; ++r) {
            int lin = r * 256 + tid;
            int s = lin >> 4, e = lin & 15;
            float val = bf2f(vg[((size_t)(b * LQ + s)) * HID + hh * DHEAD + e0 + e]);
            Vtl[0][(s >> 5) * 512 + e * 32 + (s & 31)] = f2us(val);
        }
    }

    for (int c = 0; c < NCH; ++c) {
        const int cur = c & 1, nxt = cur ^ 1;
        const int t0 = c * CCH;
        __syncthreads();  // drains chunk-c DMA (issued last iter), M[cur] visible
        // issue DMA for c+1 (drained at NEXT barrier -> overlaps this compute)
        if (c + 1 < NCH) {
            const int t0n = t0 + CCH;
            const unsigned short* qrow =
                qs + ((size_t)(b * LQ + t0n + jrow)) * HID + hh * DHEAD + qcol;
#pragma unroll
            for (int ks = 0; ks < 4; ++ks)
                __builtin_amdgcn_global_load_lds(
                    (const __attribute__((address_space(1))) void*)(qrow + ks * 32),
                    (__attribute__((address_space(3))) void*)(&Qsl[nxt][ks * 2048 + tid * 8]),
                    16, 0, 0);
            const unsigned short* kbase = ktg + ((size_t)(bh * NCH + c + 1)) * 8192 + tid * 8;
#pragma unroll
            for (int i = 0; i < 4; ++i)
                __builtin_amdgcn_global_load_lds(
                    (const __attribute__((address_space(1))) void*)(kbase + i * 2048),
                    (__attribute__((address_space(3))) void*)(&Ktl[nxt][i * 2048 + tid * 8]),
                    16, 0, 0);
        }
        // early yb/o prefetch (consumed after MFMAs)
        size_t yidx[4];
        unsigned short prevy[4];
        float osv[4];
#pragma unroll
        for (int r = 0; r < 4; ++r) {
            int j = 16 * wave + lq * 4 + r;
            yidx[r] = ((size_t)(b * LQ + t0 + j)) * HID + hh * DHEAD + e0 + lm;
            prevy[r] = yb[yidx[r]];
            osv[r] = oT[(size_t)bh * LQ + t0 + j];
        }
        const float cd = cdecG[bh * NCH + c];
        // U = K''^T V : wave d-strip [32*wave, +32)
        f32x4 uacc[2] = {};
#pragma unroll
        for (int ks = 0; ks < 2; ++ks) {
            bf16x8 bfv = *(const bf16x8*)(const void*)(&Vtl[cur][ks * 512 + lm * 32 + lq * 8]);
#pragma unroll
            for (int mt = 0; mt < 2; ++mt) {
                bf16x8 af = *(const bf16x8*)(const void*)(
                    &Ktl[cur][ks * 4096 + (32 * wave + 16 * mt + lm) * 32 + lq * 8]);
                uacc[mt] = __builtin_amdgcn_mfma_f32_16x16x32_bf16(af, bfv, uacc[mt], 0, 0, 0);
            }
        }
        // Y = Qs @ M[cur] : wave j-strip [16*wave, +16)
        f32x4 yacc = {};
#pragma unroll
        for (int ks = 0; ks < 4; ++ks) {
            bf16x8 af = *(const bf16x8*)(const void*)(
                &Qsl[cur][ks * 2048 + (16 * wave + lm) * 32 + lq * 8]);
            float4 m0 = *(const float4*)(const void*)(&Ml[cur][lm * 132 + ks * 32 + lq * 8]);
            float4 m1 = *(const float4*)(const void*)(&Ml[cur][lm * 132 + ks * 32 + lq * 8 + 4]);
            __align__(16) unsigned short tmp[8];
            tmp[0] = f2us(m0.x); tmp[1] = f2us(m0.y); tmp[2] = f2us(m0.z); tmp[3] = f2us(m0.w);
            tmp[4] = f2us(m1.x); tmp[5] = f2us(m1.y); tmp[6] = f2us(m1.z); tmp[7] = f2us(m1.w);
            bf16x8 bfm = *(const bf16x8*)tmp;
            yacc = __builtin_amdgcn_mfma_f32_16x16x32_bf16(af, bfm, yacc, 0, 0, 0);
        }
        // yb += o * Y_inter
#pragma unroll
        for (int r = 0; r < 4; ++r)
            yb[yidx[r]] = f2us(bf2f(prevy[r]) + osv[r] * yacc[r]);
        // VALU-stage V for chunk c+1 into nxt buffer
        if (c + 1 < NCH) {
            const int t0n = t0 + CCH;
#pragma unroll
            for (int r = 0; r < 4; ++r) {
                int lin = r * 256 + tid;
                int s = lin >> 4, e = lin & 15;
                float val = bf2f(vg[((size_t)(b * LQ + t0n + s)) * HID + hh * DHEAD + e0 + e]);
                Vtl[nxt][(s >> 5) * 512 + e * 32 + (s & 31)] = f2us(val);
            }
        }
        // M[nxt] = cd * M[cur] + U  (write other buffer -> no barrier needed)
#pragma unroll
        for (int mt = 0; mt < 2; ++mt)
#pragma unroll
            for (int r = 0; r < 4; ++r) {
                int d = 32 * wave + 16 * mt + lq * 4 + r;
                Ml[nxt][lm * 132 + d] = cd * Ml[cur][lm * 132 + d] + uacc[mt][r];
            }
    }
}

// ---------------------------------------------------------------------------
extern "C" void kernel_launch(void* const* d_in, const int* in_sizes, int n_in,
                              void* d_out, int out_size, void* d_ws, size_t ws_size,
                              hipStream_t stream) {
    const void* x      = d_in[0];
    const void* norm_w = d_in[1];
    const void* Wq     = d_in[2];
    const void* Wk     = d_in[3];
    const void* Wv     = d_in[4];
    const void* Wbeta  = d_in[5];
    const void* bbeta  = d_in[6];
    const void* Wig    = d_in[7];
    const void* big    = d_in[8];
    const void* Wog    = d_in[9];
    const void* bog    = d_in[10];
    const void* Wout   = d_in[11];
    const void* bout   = d_in[12];

    char* ws = (char*)d_ws;
    const size_t KB = 1024, MB = 1024 * 1024;
    int*   flag    = (int*)(ws + 0);
    float* bbeta_c = (float*)(ws + 1 * KB);
    float* big_c   = (float*)(ws + 1 * KB + 32);
    float* bog_c   = (float*)(ws + 1 * KB + 64);
    float* bout_c  = (float*)(ws + 4 * KB);
    float* cdecG   = (float*)(ws + 16 * KB);            // 8 KiB
    unsigned short* Wbeta_c = (unsigned short*)(ws + 64 * KB);
    unsigned short* Wig_c   = (unsigned short*)(ws + 96 * KB);
    unsigned short* Wog_c   = (unsigned short*)(ws + 128 * KB);
    float* fT   = (float*)(ws + 1 * MB);
    float* gT   = (float*)(ws + 1 * MB + 512 * KB);
    float* oT   = (float*)(ws + 2 * MB);
    float* cosT = (float*)(ws + 2 * MB + 512 * KB);
    float* sinT = (float*)(ws + 3 * MB + 512 * KB);
    unsigned short* Wq_c   = (unsigned short*)(ws + 5 * MB);
    unsigned short* Wk_c   = (unsigned short*)(ws + 7 * MB);
    unsigned short* Wv_c   = (unsigned short*)(ws + 9 * MB);
    unsigned short* Wout_c = (unsigned short*)(ws + 11 * MB);
    __hip_bfloat16* h  = (__hip_bfloat16*)(ws + 16 * MB);   // 32 MiB; dead after QKV gemm
    unsigned short* ktg = (unsigned short*)(ws + 16 * MB);  // aliases h (32 MiB)
    unsigned short* qb = (unsigned short*)(ws + 48 * MB);
    unsigned short* kb = (unsigned short*)(ws + 80 * MB);
    unsigned short* vb = (unsigned short*)(ws + 112 * MB);
    __hip_bfloat16* yb = (__hip_bfloat16*)(ws + 144 * MB);

    detect_kernel<<<1, 64, 0, stream>>>(x, flag);
    cvt_w4_kernel<<<dim3(1024, 5), 256, 0, stream>>>(Wq, Wk, Wv, Wout,
                                                     Wq_c, Wk_c, Wv_c, Wout_c,
                                                     cosT, sinT, flag);
    cvt_small_kernel<<<101, 256, 0, stream>>>(Wbeta, Wig, Wog, bbeta, big, bog, bout,
                                              Wbeta_c, Wig_c, Wog_c,
                                              bbeta_c, big_c, bog_c, bout_c, flag);
    rmsnorm_gates_kernel<<<MROWS, 256, 0, stream>>>(
        x, norm_w, h, flag,
        (const __hip_bfloat16*)Wbeta_c, bbeta_c,
        (const __hip_bfloat16*)Wig_c, big_c,
        (const __hip_bfloat16*)Wog_c, bog_c, fT, gT, oT);

    gemm_qkv<<<dim3(MROWS / 256, 12), 512, 0, stream>>>(h, Wq_c, Wk_c, Wv_c, qb, kb, vb);

    intra_kernel<<<dim3(NCH, 32), 256, 0, stream>>>(qb, kb, vb, fT, gT, oT, cosT, sinT,
                                                    (__hip_bfloat16*)yb, ktg, cdecG);
    inter_kernel<<<dim3(32, 8), 256, 0, stream>>>(qb, ktg, vb, oT, cdecG,
                                                  (unsigned short*)yb);

    gemm_bt<<<dim3(MROWS / 256, HID / 256), 512, 0, stream>>>(
        (const __hip_bfloat16*)yb, (const __hip_bfloat16*)Wout_c, bout_c, d_out, flag);
}

// Round 12
// 447.500 us; speedup vs baseline: 1.2127x; 1.1340x over previous
//
#include <hip/hip_runtime.h>
#include <hip/hip_bf16.h>

#define BQ 4
#define LQ 4096
#define HID 1024
#define NHEAD 8
#define DHEAD 128
#define MROWS (BQ * LQ) /* 16384 */
#define CCH 64          /* chunk length */
#define NCH (LQ / CCH)  /* 64 chunks */
#define GNT 16          /* K-tiles of 64 in the 256^2 GEMMs */

typedef __bf16 bf16x8 __attribute__((ext_vector_type(8)));
typedef float f32x4 __attribute__((ext_vector_type(4)));

__device__ __forceinline__ float bf2f(unsigned short u) {
    return __uint_as_float(((unsigned int)u) << 16);
}
__device__ __forceinline__ unsigned short f2us(float f) {
    __hip_bfloat16 b = __float2bfloat16(f);
    return *reinterpret_cast<unsigned short*>(&b);
}
__device__ __forceinline__ float loadAny(const void* p, size_t i, bool isf) {
    return isf ? ((const float*)p)[i] : bf2f(((const unsigned short*)p)[i]);
}

// ---------------------------------------------------------------------------
// Dtype probe: flag=1 -> inputs are f32; flag=0 -> bf16.
// ---------------------------------------------------------------------------
__global__ void detect_kernel(const void* x, int* flag) {
    const unsigned short* u = (const unsigned short*)x;
    int t = threadIdx.x;  // 64 threads
    int cnt = 0;
#pragma unroll
    for (int s = 0; s < 64; ++s) {
        unsigned short v = u[2 * (t * 64 + s)];
        int e = (v >> 7) & 0xFF;
        cnt += (e >= 0x8A || (e != 0 && e <= 0x6E)) ? 1 : 0;
    }
#pragma unroll
    for (int m = 1; m < 64; m <<= 1) cnt += __shfl_xor(cnt, m);
    if (t == 0) *flag = (cnt > 1024) ? 1 : 0;
}

// ---------------------------------------------------------------------------
// Convert the four 1024x1024 weights to bf16; blockIdx.y==4 builds RoPE tables.
// ---------------------------------------------------------------------------
__global__ __launch_bounds__(256) void cvt_w4_kernel(
    const void* Wq, const void* Wk, const void* Wv, const void* Wout,
    unsigned short* dq, unsigned short* dk, unsigned short* dv, unsigned short* dout,
    float* __restrict__ cosT, float* __restrict__ sinT,
    const int* flagp) {
    if (blockIdx.y == 4) {
        int idx = blockIdx.x * 256 + threadIdx.x;  // 0..262143 = 4096*64
        int l = idx >> 6, i = idx & 63;
        float invf = powf(10000.0f, -(float)i * (1.0f / 64.0f));
        float fr = (float)l * invf;
        cosT[idx] = cosf(fr);
        sinT[idx] = sinf(fr);
        return;
    }
    const bool isf = (*flagp != 0);
    const void* s;
    unsigned short* d;
    switch (blockIdx.y) {
        case 0: s = Wq; d = dq; break;
        case 1: s = Wk; d = dk; break;
        case 2: s = Wv; d = dv; break;
        default: s = Wout; d = dout; break;
    }
    size_t i = ((size_t)blockIdx.x * 256 + threadIdx.x) * 4;
#pragma unroll
    for (int r = 0; r < 4; ++r) d[i + r] = f2us(loadAny(s, i + r, isf));
}

// ---------------------------------------------------------------------------
// Convert gate weights into zero-padded [256][1024] bf16 Wg_pad (rows 0..23 =
// beta/ig/og, rows 24..255 zero) and biases (-> f32).
// ---------------------------------------------------------------------------
__global__ __launch_bounds__(256) void cvt_small_kernel(
    const void* Wbeta, const void* Wig, const void* Wog,
    const void* bbeta, const void* big, const void* bog, const void* bout,
    unsigned short* __restrict__ Wg_pad,
    float* dbb, float* dbi, float* dbo, float* dbout,
    const int* flagp) {
    const bool isf = (*flagp != 0);
    int gid = blockIdx.x * 256 + threadIdx.x;
    if (gid < 24576) {
        int seg = gid >> 13, off = gid & 8191;
        const void* s = (seg == 0) ? Wbeta : (seg == 1) ? Wig : Wog;
        Wg_pad[gid] = f2us(loadAny(s, off, isf));
    } else if (gid < 25624) {
        int j = gid - 24576;
        if (j < 8) dbb[j] = loadAny(bbeta, j, isf);
        else if (j < 16) dbi[j - 8] = loadAny(big, j - 8, isf);
        else if (j < 24) dbo[j - 16] = loadAny(bog, j - 16, isf);
        else if (j < 24 + 1024) dbout[j - 24] = loadAny(bout, j - 24, isf);
    } else {
        int z = gid - 25624;
        if (z < 29696) {  // (256-24)*1024/8
            uint4 zz = make_uint4(0, 0, 0, 0);
            *(uint4*)(Wg_pad + 24576 + (size_t)z * 8) = zz;
        }
    }
}

// ---------------------------------------------------------------------------
// Pure streaming RMSNorm: h = x*rsqrt(mean(x^2)+1e-6)*w (bf16 out).
// ---------------------------------------------------------------------------
__global__ __launch_bounds__(256) void rmsnorm_kernel(
    const void* __restrict__ xin, const void* __restrict__ win,
    __hip_bfloat16* __restrict__ h, const int* __restrict__ flagp) {
    const bool isf = (*flagp != 0);
    const int row = blockIdx.x;
    const int tid = threadIdx.x;
    const int lane = tid & 63, wave = tid >> 6;
    const size_t base = (size_t)row * HID;
    float x0, x1, x2, x3;
    if (isf) {
        float4 u = ((const float4*)((const float*)xin + base))[tid];
        x0 = u.x; x1 = u.y; x2 = u.z; x3 = u.w;
    } else {
        ushort4 u = ((const ushort4*)((const unsigned short*)xin + base))[tid];
        x0 = bf2f(u.x); x1 = bf2f(u.y); x2 = bf2f(u.z); x3 = bf2f(u.w);
    }
    float ss = x0 * x0 + x1 * x1 + x2 * x2 + x3 * x3;
#pragma unroll
    for (int m = 1; m < 64; m <<= 1) ss += __shfl_xor(ss, m);
    __shared__ float wsum[4];
    if (lane == 0) wsum[wave] = ss;
    __syncthreads();
    float tot = wsum[0] + wsum[1] + wsum[2] + wsum[3];
    float inv = rsqrtf(tot * (1.0f / HID) + 1e-6f);
    float w0, w1, w2, w3;
    if (isf) {
        float4 u = ((const float4*)win)[tid];
        w0 = u.x; w1 = u.y; w2 = u.z; w3 = u.w;
    } else {
        ushort4 u = ((const ushort4*)win)[tid];
        w0 = bf2f(u.x); w1 = bf2f(u.y); w2 = bf2f(u.z); w3 = bf2f(u.w);
    }
    ushort4 ho4;
    ho4.x = f2us(x0 * inv * w0);
    ho4.y = f2us(x1 * inv * w1);
    ho4.z = f2us(x2 * inv * w2);
    ho4.w = f2us(x3 * inv * w3);
    *(ushort4*)((unsigned short*)h + base + tid * 4) = ho4;
}

// ---------------------------------------------------------------------------
// 256x256 (BK=64) 8-wave 4-phase GEMM core with REGISTER-HELD fragments.
// (verified round 5: race-clean, bank-conflict-free, 24 unique ds_reads/K-tile)
// ---------------------------------------------------------------------------
__device__ __forceinline__ void g256_stage_half(const unsigned short* __restrict__ src,
                                                unsigned short* lds, int tid) {
#pragma unroll
    for (int l = 0; l < 2; ++l) {
        int L = l * 512 + tid;          // 1024 granules = 128 rows x 8
        int r = L >> 3, g = L & 7;
        int gs = g ^ (r & 7);           // pre-swizzled global source
        __builtin_amdgcn_global_load_lds(
            (const __attribute__((address_space(1))) void*)(src + (size_t)r * HID + gs * 8),
            (__attribute__((address_space(3))) void*)(lds + L * 8), 16, 0, 0);
    }
}

#define G256_SEAL() __builtin_amdgcn_sched_barrier(0)
#define G256_BARRIER()            \
    do {                          \
        G256_SEAL();              \
        __builtin_amdgcn_s_barrier(); \
        G256_SEAL();              \
    } while (0)
#define G256_LGKM0()                                        \
    do {                                                    \
        asm volatile("s_waitcnt lgkmcnt(0)" ::: "memory");  \
        G256_SEAL();                                        \
    } while (0)

__device__ __forceinline__ void g256_read_A(const unsigned short* Ac, int mq,
                                            int wr, int lm, int lq, bf16x8 (&bA)[4][2]) {
#pragma unroll
    for (int i = 0; i < 4; ++i) {
        const int row = mq * 128 + wr * 64 + i * 16 + lm;
#pragma unroll
        for (int kk = 0; kk < 2; ++kk) {
            const int gsw = (kk * 4 + lq) ^ (lm & 7);
            bA[i][kk] = *(const bf16x8*)(const void*)(Ac + row * 64 + gsw * 8);
        }
    }
}
__device__ __forceinline__ void g256_read_B(const unsigned short* Bc, int nq,
                                            int wc, int lm, int lq, bf16x8 (&bB)[2][2]) {
#pragma unroll
    for (int j = 0; j < 2; ++j) {
        const int row = nq * 128 + wc * 32 + j * 16 + lm;
#pragma unroll
        for (int kk = 0; kk < 2; ++kk) {
            const int gsw = (kk * 4 + lq) ^ (lm & 7);
            bB[j][kk] = *(const bf16x8*)(const void*)(Bc + row * 64 + gsw * 8);
        }
    }
}
__device__ __forceinline__ void g256_mfma(int mq, int nq, const bf16x8 (&bA)[4][2],
                                          const bf16x8 (&bB)[2][2], f32x4 (&acc)[8][4]) {
    __builtin_amdgcn_s_setprio(1);
#pragma unroll
    for (int i = 0; i < 4; ++i)
#pragma unroll
        for (int j = 0; j < 2; ++j)
#pragma unroll
            for (int kk = 0; kk < 2; ++kk)
                acc[mq * 4 + i][nq * 2 + j] = __builtin_amdgcn_mfma_f32_16x16x32_bf16(
                    bA[i][kk], bB[j][kk], acc[mq * 4 + i][nq * 2 + j], 0, 0, 0);
    __builtin_amdgcn_s_setprio(0);
}

__device__ __forceinline__ void g256_core(const unsigned short* __restrict__ A,
                                          const unsigned short* __restrict__ W,
                                          unsigned short* As, unsigned short* Bs,
                                          int m0, int tid, f32x4 (&acc)[8][4]) {
    const int lane = tid & 63, wid = tid >> 6;
    const int wr = wid >> 2, wc = wid & 3;
    const int lm = lane & 15, lq = lane >> 4;
    // prologue: tile0 all 4 halves -> buf0, full drain, barrier.
    g256_stage_half(A + (size_t)m0 * HID, As, tid);                  // A0
    g256_stage_half(W, Bs, tid);                                     // B0
    g256_stage_half(W + (size_t)128 * HID, Bs + 8192, tid);          // B1
    g256_stage_half(A + (size_t)(m0 + 128) * HID, As + 8192, tid);   // A1
    G256_SEAL();
    asm volatile("s_waitcnt vmcnt(0)" ::: "memory");
    G256_BARRIER();
    for (int t = 0; t < GNT; ++t) {
        unsigned short* Ac = As + (t & 1) * 16384;
        unsigned short* Bc = Bs + (t & 1) * 16384;
        unsigned short* An = As + ((t & 1) ^ 1) * 16384;
        unsigned short* Bn = Bs + ((t & 1) ^ 1) * 16384;
        const int kn = (t + 1) * 64;
        const bool pf = (t + 1 < GNT);
        bf16x8 bA[4][2], bB0[2][2], bB1[2][2];
        // ---- ph0: read A(mq0)+B(nq0); stage (t+1).A0,(t+1).B0 ----
        g256_read_A(Ac, 0, wr, lm, lq, bA);
        g256_read_B(Bc, 0, wc, lm, lq, bB0);
        if (pf) {
            g256_stage_half(A + (size_t)m0 * HID + kn, An, tid);
            g256_stage_half(W + kn, Bn, tid);
        }
        G256_BARRIER();
        G256_LGKM0();
        g256_mfma(0, 0, bA, bB0, acc);
        G256_BARRIER();
        // ---- ph1: read B(nq1); stage (t+1).B1 ----
        g256_read_B(Bc, 1, wc, lm, lq, bB1);
        if (pf) g256_stage_half(W + (size_t)128 * HID + kn, Bn + 8192, tid);
        G256_BARRIER();
        G256_LGKM0();
        g256_mfma(0, 1, bA, bB1, acc);
        G256_BARRIER();
        // ---- ph2: read A(mq1); stage (t+1).A1 ----
        g256_read_A(Ac, 1, wr, lm, lq, bA);
        if (pf) g256_stage_half(A + (size_t)(m0 + 128) * HID + kn, An + 8192, tid);
        G256_BARRIER();
        G256_LGKM0();
        g256_mfma(1, 0, bA, bB0, acc);
        G256_BARRIER();
        // ---- ph3: no ds_reads, no staging; drain tile t+1's stages ----
        g256_mfma(1, 1, bA, bB1, acc);
        G256_SEAL();
        if (pf) asm volatile("s_waitcnt vmcnt(0)" ::: "memory");
        G256_BARRIER();
    }
}

// ---------------------------------------------------------------------------
// Merged QKV+gates GEMM: blockIdx.y in [0,13).  y<12 -> weight y>>2, column
// block (y&3)*256, bf16 C-write.  y==12 -> zero-padded gate weights; epilogue
// applies bias+sigmoid and scatters the 24 valid columns into fT/gT/oT.
// ---------------------------------------------------------------------------
__global__ __launch_bounds__(512) void gemm_qkv(const __hip_bfloat16* __restrict__ A,
                                                const unsigned short* __restrict__ Wqc,
                                                const unsigned short* __restrict__ Wkc,
                                                const unsigned short* __restrict__ Wvc,
                                                const unsigned short* __restrict__ Wg_pad,
                                                unsigned short* __restrict__ qb,
                                                unsigned short* __restrict__ kb,
                                                unsigned short* __restrict__ vb,
                                                const float* __restrict__ bbeta,
                                                const float* __restrict__ big,
                                                const float* __restrict__ bog,
                                                float* __restrict__ fT,
                                                float* __restrict__ gT,
                                                float* __restrict__ oT) {
    __shared__ __align__(16) unsigned short As[2 * 16384];
    __shared__ __align__(16) unsigned short Bs[2 * 16384];
    const int nblk = blockIdx.y;
    const int sel = nblk >> 2;           // 0,1,2 = q,k,v; 3 = gates
    const int nl0 = (nblk & 3) * 256;    // 0 for gate block
    const unsigned short* W =
        (sel == 0) ? Wqc + (size_t)nl0 * HID
      : (sel == 1) ? Wkc + (size_t)nl0 * HID
      : (sel == 2) ? Wvc + (size_t)nl0 * HID
                   : Wg_pad;
    const int tid = threadIdx.x;
    const int lane = tid & 63, wid = tid >> 6;
    const int wr = wid >> 2, wc = wid & 3;
    const int lm = lane & 15, lq = lane >> 4;
    const int m0 = blockIdx.x * 256;
    f32x4 acc[8][4] = {};
    g256_core((const unsigned short*)A, W, As, Bs, m0, tid, acc);
    if (sel < 3) {
        unsigned short* C = (sel == 0) ? qb : (sel == 1) ? kb : vb;
#pragma unroll
        for (int mq = 0; mq < 2; ++mq)
#pragma unroll
            for (int i = 0; i < 4; ++i)
#pragma unroll
                for (int nq = 0; nq < 2; ++nq)
#pragma unroll
                    for (int j = 0; j < 2; ++j) {
                        const int col = nl0 + nq * 128 + wc * 32 + j * 16 + lm;
#pragma unroll
                        for (int r = 0; r < 4; ++r) {
                            const int rowg = m0 + mq * 128 + wr * 64 + i * 16 + lq * 4 + r;
                            C[(size_t)rowg * HID + col] = f2us(acc[mq * 4 + i][nq * 2 + j][r]);
                        }
                    }
    } else {
        // gates: cols 0..23 valid (nq=0 quadrant only)
#pragma unroll
        for (int j = 0; j < 2; ++j) {
            const int col = wc * 32 + j * 16 + lm;  // nq=0 cols only
            if (col < 24) {
                const float bb = (col < 8) ? bbeta[col]
                               : (col < 16) ? big[col - 8]
                                            : bog[col - 16];
                const int hh = col & 7;
                float* dst = (col < 8) ? fT : (col < 16) ? gT : oT;
#pragma unroll
                for (int mq = 0; mq < 2; ++mq)
#pragma unroll
                    for (int i = 0; i < 4; ++i)
#pragma unroll
                        for (int r = 0; r < 4; ++r) {
                            const int rowg = m0 + mq * 128 + wr * 64 + i * 16 + lq * 4 + r;
                            const int b = rowg >> 12, l = rowg & (LQ - 1);
                            float s = acc[mq * 4 + i][j][r] + bb;  // nq=0 -> slot j, lane r
                            s = 1.0f / (1.0f + expf(-s));
                            dst[((size_t)(b * NHEAD + hh)) * LQ + l] = s;
                        }
            }
        }
    }
}

// ---------------------------------------------------------------------------
// Final GEMM on the 256^2 core: C = A W^T + bias; C f32 when (*flagp).
// ---------------------------------------------------------------------------
__global__ __launch_bounds__(512) void gemm_bt(const __hip_bfloat16* __restrict__ A,
                                               const __hip_bfloat16* __restrict__ W,
                                               const float* __restrict__ bias,
                                               void* __restrict__ C,
                                               const int* __restrict__ flagp) {
    __shared__ __align__(16) unsigned short As[2 * 16384];
    __shared__ __align__(16) unsigned short Bs[2 * 16384];
    const bool f32out = (*flagp != 0);
    const int tid = threadIdx.x;
    const int lane = tid & 63, wid = tid >> 6;
    const int wr = wid >> 2, wc = wid & 3;
    const int lm = lane & 15, lq = lane >> 4;
    const int m0 = blockIdx.x * 256;
    const int nl0 = blockIdx.y * 256;
    f32x4 acc[8][4] = {};
    g256_core((const unsigned short*)A, (const unsigned short*)W + (size_t)nl0 * HID,
              As, Bs, m0, tid, acc);
#pragma unroll
    for (int mq = 0; mq < 2; ++mq)
#pragma unroll
        for (int i = 0; i < 4; ++i)
#pragma unroll
            for (int nq = 0; nq < 2; ++nq)
#pragma unroll
                for (int j = 0; j < 2; ++j) {
                    const int col = nl0 + nq * 128 + wc * 32 + j * 16 + lm;
                    const float bv = bias[col];
#pragma unroll
                    for (int r = 0; r < 4; ++r) {
                        const int rowg = m0 + mq * 128 + wr * 64 + i * 16 + lq * 4 + r;
                        const size_t idx = (size_t)rowg * HID + col;
                        const float val = acc[mq * 4 + i][nq * 2 + j][r] + bv;
                        if (f32out) ((float*)C)[idx] = val;
                        else ((__hip_bfloat16*)C)[idx] = __float2bfloat16(val);
                    }
                }
}

// ---------------------------------------------------------------------------
// INTRA kernel + prep. Q is never staged to LDS: each lane builds its MFMA
// A-fragment of rope(q) in registers (pair i/i+64 lives in the same thread)
// and writes scaled qb back from the same registers. LDS = Kr+Vt+Sp ~46 KB
// -> 3 blocks/CU (was 2).
// ---------------------------------------------------------------------------
__global__ __launch_bounds__(256) void intra_kernel(
    unsigned short* __restrict__ qg, const unsigned short* __restrict__ kg,
    const unsigned short* __restrict__ vg,
    const float* __restrict__ fT, const float* __restrict__ gT, const float* __restrict__ oT,
    const float* __restrict__ cosT, const float* __restrict__ sinT,
    __hip_bfloat16* __restrict__ yb,
    unsigned short* __restrict__ ktg, float* __restrict__ cdecG) {
    const int chunk = blockIdx.x;        // 0..63
    const int bh = blockIdx.y;           // 0..31
    const int b = bh >> 3, hh = bh & 7;
    const int t0 = chunk * CCH;
    const int tid = threadIdx.x;
    const int lane = tid & 63, wave = tid >> 6;
    const int lm = lane & 15, lq = lane >> 4;
    __shared__ unsigned short Kr[64 * 136];
    __shared__ unsigned short Vt[128 * 72];
    __shared__ unsigned short Sp[64 * 72];
    __shared__ float Lp[64], aS[64], osh[64], w2s[64], qscs[64];

    // phase 0: gates + decay prefix (wave 0)
    if (tid < 64) {
        float f = fT[(size_t)bh * LQ + t0 + tid];
        float g = gT[(size_t)bh * LQ + t0 + tid];
        osh[tid] = oT[(size_t)bh * LQ + t0 + tid];
        float lf = __logf(f);
#pragma unroll
        for (int off = 1; off < 64; off <<= 1) {
            float v = __shfl_up(lf, off);
            if (lane >= off) lf += v;
        }
        float tot = __shfl(lf, 63);
        Lp[tid] = lf;
        aS[tid] = g * 0.08838834764831845f;  // g / sqrt(128)
        w2s[tid] = __expf(tot - lf) * (g * 0.08838834764831845f);
        qscs[tid] = __expf(lf);
        if (tid == 63) cdecG[bh * NCH + chunk] = __expf(lf);
    }
    __syncthreads();  // B0

    // phase 1a: Q fragments in registers + scaled write-back.
    // Lane owns row (16*wave+lm), k-cols ks*32+lq*8+[0,8) for ks=0..3.
    bf16x8 af[4];
    {
        const int jr = 16 * wave + lm;
        const int gt = t0 + jr;
        const size_t qbase = ((size_t)(b * LQ + gt)) * HID + hh * DHEAD;
        uint4 qraw[4];
#pragma unroll
        for (int ks = 0; ks < 4; ++ks)
            qraw[ks] = *(const uint4*)(qg + qbase + ks * 32 + lq * 8);
        const unsigned short* q0 = (const unsigned short*)&qraw[0];
        const unsigned short* q1 = (const unsigned short*)&qraw[1];
        const unsigned short* q2 = (const unsigned short*)&qraw[2];
        const unsigned short* q3 = (const unsigned short*)&qraw[3];
        const float sc = qscs[jr];
        __align__(16) unsigned short fr[4][8];
        __align__(16) unsigned short qo[4][8];
#pragma unroll
        for (int u = 0; u < 8; ++u) {
            int i = lq * 8 + u;          // pair (i, i+64) for ks 0<->2
            int i2 = 32 + lq * 8 + u;    // pair for ks 1<->3
            float c0 = cosT[gt * 64 + i], s0 = sinT[gt * 64 + i];
            float c1 = cosT[gt * 64 + i2], s1 = sinT[gt * 64 + i2];
            float a = bf2f(q0[u]), bq = bf2f(q2[u]);
            float rc = a * c0 - bq * s0, rs = a * s0 + bq * c0;
            fr[0][u] = f2us(rc); fr[2][u] = f2us(rs);
            qo[0][u] = f2us(rc * sc); qo[2][u] = f2us(rs * sc);
            float a1 = bf2f(q1[u]), bq1 = bf2f(q3[u]);
            float rc1 = a1 * c1 - bq1 * s1, rs1 = a1 * s1 + bq1 * c1;
            fr[1][u] = f2us(rc1); fr[3][u] = f2us(rs1);
            qo[1][u] = f2us(rc1 * sc); qo[3][u] = f2us(rs1 * sc);
        }
#pragma unroll
        for (int ks = 0; ks < 4; ++ks) {
            af[ks] = *(const bf16x8*)fr[ks];
            *(uint4*)(qg + qbase + ks * 32 + lq * 8) = *(const uint4*)qo[ks];
        }
    }
    // phase 1b: rope-stage K into LDS
#pragma unroll
    for (int r = 0; r < 16; ++r) {
        int pid = r * 256 + tid;
        int t = pid >> 6, i = pid & 63;
        int gt = t0 + t;
        size_t gidx = ((size_t)(b * LQ + gt)) * HID + hh * DHEAD + i;
        float c = cosT[gt * 64 + i], s = sinT[gt * 64 + i];
        float k1 = bf2f(kg[gidx]), k2 = bf2f(kg[gidx + 64]);
        Kr[t * 136 + i] = f2us(k1 * c - k2 * s);
        Kr[t * 136 + i + 64] = f2us(k1 * s + k2 * c);
    }
    // stage V transposed: Vt[e][s]
#pragma unroll
    for (int r = 0; r < 32; ++r) {
        int lin = r * 256 + tid;
        int sI = lin >> 7, e = lin & 127;
        float val = bf2f(vg[((size_t)(b * LQ + t0 + sI)) * HID + hh * DHEAD + e]);
        Vt[e * 72 + sI] = f2us(val);
    }
    __syncthreads();  // B1

    // S = Q K^T (64x64, K=128); wave j-strip [16*wave,+16), Q from registers
    f32x4 sacc[4] = {};
#pragma unroll
    for (int ks = 0; ks < 4; ++ks) {
#pragma unroll
        for (int nt = 0; nt < 4; ++nt) {
            bf16x8 bf = *(const bf16x8*)(const void*)(Kr + (nt * 16 + lm) * 136 + ks * 32 + lq * 8);
            sacc[nt] = __builtin_amdgcn_mfma_f32_16x16x32_bf16(af[ks], bf, sacc[nt], 0, 0, 0);
        }
    }
    // mask + decay/gate scale, store S' bf16 [j][s]
#pragma unroll
    for (int nt = 0; nt < 4; ++nt) {
#pragma unroll
        for (int r = 0; r < 4; ++r) {
            int j = 16 * wave + lq * 4 + r;
            int s = nt * 16 + lm;
            float v = 0.0f;
            if (j >= s) v = sacc[nt][r] * __expf(Lp[j] - Lp[s]) * aS[s];
            Sp[j * 72 + s] = f2us(v);
        }
    }
    // PREP: KtG[ks][d][32] = w2_s * Kr[s][d]
    {
        unsigned short* krec = ktg + ((size_t)(bh * NCH + chunk)) * 8192;
#pragma unroll
        for (int r = 0; r < 2; ++r) {
            int lin16 = r * 256 + tid;
            int ks = lin16 >> 8;
            int d = (lin16 & 255) >> 1;
            int cc0 = (lin16 & 1) * 16;
            __align__(16) unsigned short out[16];
#pragma unroll
            for (int u = 0; u < 16; ++u) {
                int s = ks * 32 + cc0 + u;
                out[u] = f2us(w2s[s] * bf2f(Kr[s * 136 + d]));
            }
            uint4* dst = (uint4*)(krec + (size_t)lin16 * 16);
            dst[0] = *(const uint4*)(out);
            dst[1] = *(const uint4*)(out + 8);
        }
    }
    __syncthreads();  // B2

    // Y_intra = S' V  (64x128, K=64)
    f32x4 ya[8] = {};
#pragma unroll
    for (int ks = 0; ks < 2; ++ks) {
        bf16x8 afs = *(const bf16x8*)(const void*)(Sp + (16 * wave + lm) * 72 + ks * 32 + lq * 8);
#pragma unroll
        for (int nt = 0; nt < 8; ++nt) {
            bf16x8 bf = *(const bf16x8*)(const void*)(Vt + (nt * 16 + lm) * 72 + ks * 32 + lq * 8);
            ya[nt] = __builtin_amdgcn_mfma_f32_16x16x32_bf16(afs, bf, ya[nt], 0, 0, 0);
        }
    }
#pragma unroll
    for (int nt = 0; nt < 8; ++nt) {
#pragma unroll
        for (int r = 0; r < 4; ++r) {
            int j = 16 * wave + lq * 4 + r;
            int e = nt * 16 + lm;
            size_t row = (size_t)(b * LQ + t0 + j);
            yb[row * HID + hh * DHEAD + e] = __float2bfloat16(osh[j] * ya[nt][r]);
        }
    }
}

// ---------------------------------------------------------------------------
// INTER kernel: ONE barrier per chunk. State M double-buffered in LDS (read
// M[c&1], write M[(c+1)&1]) so no second barrier is needed; Q/K DMA for c+1
// issued AFTER the top barrier so it stays in flight through chunk c's
// compute and is drained by the NEXT barrier (true prefetch overlap).
// yb RMW values prefetched right after the barrier to hide their latency.
// ---------------------------------------------------------------------------
__global__ __launch_bounds__(256) void inter_kernel(
    const unsigned short* __restrict__ qs,   // exp(Lp_j)*rope(q), [row][128]
    const unsigned short* __restrict__ ktg,  // [bh][chunk][ks][d][32]
    const unsigned short* __restrict__ vg,
    const float* __restrict__ oT, const float* __restrict__ cdecG,
    unsigned short* __restrict__ yb) {
    const int bh = blockIdx.x;       // 0..31
    const int esplit = blockIdx.y;   // 0..7
    const int e0 = esplit * 16;
    const int b = bh >> 3, hh = bh & 7;
    const int tid = threadIdx.x;
    const int lane = tid & 63, wave = tid >> 6;
    const int lm = lane & 15, lq = lane >> 4;
    __shared__ __align__(16) unsigned short Qsl[2][8192];  // [ks(4)][j(64)][32]
    __shared__ __align__(16) unsigned short Ktl[2][8192];  // [ks(2)][d(128)][32]
    __shared__ __align__(16) unsigned short Vtl[2][1024];  // [ks(2)][e(16)][32]
    __shared__ __align__(16) float Ml[2][16 * 132];        // M^T [e][d], stride 132

    for (int i = tid; i < 16 * 132; i += 256) Ml[0][i] = 0.0f;

    const int jrow = tid >> 2;
    const int qcol = (tid & 3) * 8;
    // prologue: DMA chunk 0 into buf 0, VALU-stage V0
    {
        const unsigned short* qrow =
            qs + ((size_t)(b * LQ + jrow)) * HID + hh * DHEAD + qcol;
#pragma unroll
        for (int ks = 0; ks < 4; ++ks)
            __builtin_amdgcn_global_load_lds(
                (const __attribute__((address_space(1))) void*)(qrow + ks * 32),
                (__attribute__((address_space(3))) void*)(&Qsl[0][ks * 2048 + tid * 8]),
                16, 0, 0);
        const unsigned short* kbase = ktg + ((size_t)(bh * NCH)) * 8192 + tid * 8;
#pragma unroll
        for (int i = 0; i < 4; ++i)
            __builtin_amdgcn_global_load_lds(
                (const __attribute__((address_space(1))) void*)(kbase + i * 2048),
                (__attribute__((address_space(3))) void*)(&Ktl[0][i * 2048 + tid * 8]),
                16, 0, 0);
#pragma unroll
        for (int r = 0; r < 4; ++r) {
            int lin = r * 256 + tid;
            int s = lin >> 4, e = lin & 15;
            float val = bf2f(vg[((size_t)(b * LQ + s)) * HID + hh * DHEAD + e0 + e]);
            Vtl[0][(s >> 5) * 512 + e * 32 + (s & 31)] = f2us(val);
        }
    }

    for (int c = 0; c < NCH; ++c) {
        const int cur = c & 1, nxt = cur ^ 1;
        const int t0 = c * CCH;
        __syncthreads();  // drains chunk-c DMA (issued last iter), M[cur] visible
        // issue DMA for c+1 (drained at NEXT barrier -> overlaps this compute)
        if (c + 1 < NCH) {
            const int t0n = t0 + CCH;
            const unsigned short* qrow =
                qs + ((size_t)(b * LQ + t0n + jrow)) * HID + hh * DHEAD + qcol;
#pragma unroll
            for (int ks = 0; ks < 4; ++ks)
                __builtin_amdgcn_global_load_lds(
                    (const __attribute__((address_space(1))) void*)(qrow + ks * 32),
                    (__attribute__((address_space(3))) void*)(&Qsl[nxt][ks * 2048 + tid * 8]),
                    16, 0, 0);
            const unsigned short* kbase = ktg + ((size_t)(bh * NCH + c + 1)) * 8192 + tid * 8;
#pragma unroll
            for (int i = 0; i < 4; ++i)
                __builtin_amdgcn_global_load_lds(
                    (const __attribute__((address_space(1))) void*)(kbase + i * 2048),
                    (__attribute__((address_space(3))) void*)(&Ktl[nxt][i * 2048 + tid * 8]),
                    16, 0, 0);
        }
        // early yb/o prefetch (consumed after MFMAs)
        size_t yidx[4];
        unsigned short prevy[4];
        float osv[4];
#pragma unroll
        for (int r = 0; r < 4; ++r) {
            int j = 16 * wave + lq * 4 + r;
            yidx[r] = ((size_t)(b * LQ + t0 + j)) * HID + hh * DHEAD + e0 + lm;
            prevy[r] = yb[yidx[r]];
            osv[r] = oT[(size_t)bh * LQ + t0 + j];
        }
        const float cd = cdecG[bh * NCH + c];
        // U = K''^T V : wave d-strip [32*wave, +32)
        f32x4 uacc[2] = {};
#pragma unroll
        for (int ks = 0; ks < 2; ++ks) {
            bf16x8 bfv = *(const bf16x8*)(const void*)(&Vtl[cur][ks * 512 + lm * 32 + lq * 8]);
#pragma unroll
            for (int mt = 0; mt < 2; ++mt) {
                bf16x8 af = *(const bf16x8*)(const void*)(
                    &Ktl[cur][ks * 4096 + (32 * wave + 16 * mt + lm) * 32 + lq * 8]);
                uacc[mt] = __builtin_amdgcn_mfma_f32_16x16x32_bf16(af, bfv, uacc[mt], 0, 0, 0);
            }
        }
        // Y = Qs @ M[cur] : wave j-strip [16*wave, +16)
        f32x4 yacc = {};
#pragma unroll
        for (int ks = 0; ks < 4; ++ks) {
            bf16x8 af = *(const bf16x8*)(const void*)(
                &Qsl[cur][ks * 2048 + (16 * wave + lm) * 32 + lq * 8]);
            float4 m0 = *(const float4*)(const void*)(&Ml[cur][lm * 132 + ks * 32 + lq * 8]);
            float4 m1 = *(const float4*)(const void*)(&Ml[cur][lm * 132 + ks * 32 + lq * 8 + 4]);
            __align__(16) unsigned short tmp[8];
            tmp[0] = f2us(m0.x); tmp[1] = f2us(m0.y); tmp[2] = f2us(m0.z); tmp[3] = f2us(m0.w);
            tmp[4] = f2us(m1.x); tmp[5] = f2us(m1.y); tmp[6] = f2us(m1.z); tmp[7] = f2us(m1.w);
            bf16x8 bfm = *(const bf16x8*)tmp;
            yacc = __builtin_amdgcn_mfma_f32_16x16x32_bf16(af, bfm, yacc, 0, 0, 0);
        }
        // yb += o * Y_inter
#pragma unroll
        for (int r = 0; r < 4; ++r)
            yb[yidx[r]] = f2us(bf2f(prevy[r]) + osv[r] * yacc[r]);
        // VALU-stage V for chunk c+1 into nxt buffer
        if (c + 1 < NCH) {
            const int t0n = t0 + CCH;
#pragma unroll
            for (int r = 0; r < 4; ++r) {
                int lin = r * 256 + tid;
                int s = lin >> 4, e = lin & 15;
                float val = bf2f(vg[((size_t)(b * LQ + t0n + s)) * HID + hh * DHEAD + e0 + e]);
                Vtl[nxt][(s >> 5) * 512 + e * 32 + (s & 31)] = f2us(val);
            }
        }
        // M[nxt] = cd * M[cur] + U  (write other buffer -> no barrier needed)
#pragma unroll
        for (int mt = 0; mt < 2; ++mt)
#pragma unroll
            for (int r = 0; r < 4; ++r) {
                int d = 32 * wave + 16 * mt + lq * 4 + r;
                Ml[nxt][lm * 132 + d] = cd * Ml[cur][lm * 132 + d] + uacc[mt][r];
            }
    }
}

// ---------------------------------------------------------------------------
extern "C" void kernel_launch(void* const* d_in, const int* in_sizes, int n_in,
                              void* d_out, int out_size, void* d_ws, size_t ws_size,
                              hipStream_t stream) {
    const void* x      = d_in[0];
    const void* norm_w = d_in[1];
    const void* Wq     = d_in[2];
    const void* Wk     = d_in[3];
    const void* Wv     = d_in[4];
    const void* Wbeta  = d_in[5];
    const void* bbeta  = d_in[6];
    const void* Wig    = d_in[7];
    const void* big    = d_in[8];
    const void* Wog    = d_in[9];
    const void* bog    = d_in[10];
    const void* Wout   = d_in[11];
    const void* bout   = d_in[12];

    char* ws = (char*)d_ws;
    const size_t KB = 1024, MB = 1024 * 1024;
    int*   flag    = (int*)(ws + 0);
    float* bbeta_c = (float*)(ws + 1 * KB);
    float* big_c   = (float*)(ws + 1 * KB + 32);
    float* bog_c   = (float*)(ws + 1 * KB + 64);
    float* bout_c  = (float*)(ws + 4 * KB);
    float* cdecG   = (float*)(ws + 16 * KB);            // 8 KiB
    float* fT   = (float*)(ws + 1 * MB);
    float* gT   = (float*)(ws + 1 * MB + 512 * KB);
    float* oT   = (float*)(ws + 2 * MB);
    float* cosT = (float*)(ws + 2 * MB + 512 * KB);
    float* sinT = (float*)(ws + 3 * MB + 512 * KB);
    unsigned short* Wq_c   = (unsigned short*)(ws + 5 * MB);
    unsigned short* Wk_c   = (unsigned short*)(ws + 7 * MB);
    unsigned short* Wv_c   = (unsigned short*)(ws + 9 * MB);
    unsigned short* Wout_c = (unsigned short*)(ws + 11 * MB);
    unsigned short* Wg_pad = (unsigned short*)(ws + 13 * MB);  // 512 KiB padded gates
    __hip_bfloat16* h  = (__hip_bfloat16*)(ws + 16 * MB);   // 32 MiB; dead after QKV gemm
    unsigned short* ktg = (unsigned short*)(ws + 16 * MB);  // aliases h (32 MiB)
    unsigned short* qb = (unsigned short*)(ws + 48 * MB);
    unsigned short* kb = (unsigned short*)(ws + 80 * MB);
    unsigned short* vb = (unsigned short*)(ws + 112 * MB);
    __hip_bfloat16* yb = (__hip_bfloat16*)(ws + 144 * MB);

    detect_kernel<<<1, 64, 0, stream>>>(x, flag);
    cvt_w4_kernel<<<dim3(1024, 5), 256, 0, stream>>>(Wq, Wk, Wv, Wout,
                                                     Wq_c, Wk_c, Wv_c, Wout_c,
                                                     cosT, sinT, flag);
    cvt_small_kernel<<<217, 256, 0, stream>>>(Wbeta, Wig, Wog, bbeta, big, bog, bout,
                                              Wg_pad,
                                              bbeta_c, big_c, bog_c, bout_c, flag);
    rmsnorm_kernel<<<MROWS, 256, 0, stream>>>(x, norm_w, h, flag);

    gemm_qkv<<<dim3(MROWS / 256, 13), 512, 0, stream>>>(
        h, Wq_c, Wk_c, Wv_c, Wg_pad, qb, kb, vb,
        bbeta_c, big_c, bog_c, fT, gT, oT);

    intra_kernel<<<dim3(NCH, 32), 256, 0, stream>>>(qb, kb, vb, fT, gT, oT, cosT, sinT,
                                                    (__hip_bfloat16*)yb, ktg, cdecG);
    inter_kernel<<<dim3(32, 8), 256, 0, stream>>>(qb, ktg, vb, oT, cdecG,
                                                  (unsigned short*)yb);

    gemm_bt<<<dim3(MROWS / 256, HID / 256), 512, 0, stream>>>(
        (const __hip_bfloat16*)yb, (const __hip_bfloat16*)Wout_c, bout_c, d_out, flag);
}

// Round 15
// 438.628 us; speedup vs baseline: 1.2372x; 1.0202x over previous
//
#include <hip/hip_runtime.h>
#include <hip/hip_bf16.h>

#define BQ 4
#define LQ 4096
#define HID 1024
#define NHEAD 8
#define DHEAD 128
#define MROWS (BQ * LQ) /* 16384 */
#define CCH 64          /* chunk length */
#define NCH (LQ / CCH)  /* 64 chunks */
#define GNT 16          /* K-tiles of 64 in the 256^2 GEMMs */

typedef __bf16 bf16x8 __attribute__((ext_vector_type(8)));
typedef float f32x4 __attribute__((ext_vector_type(4)));

__device__ __forceinline__ float bf2f(unsigned short u) {
    return __uint_as_float(((unsigned int)u) << 16);
}
__device__ __forceinline__ unsigned short f2us(float f) {
    __hip_bfloat16 b = __float2bfloat16(f);
    return *reinterpret_cast<unsigned short*>(&b);
}
__device__ __forceinline__ float loadAny(const void* p, size_t i, bool isf) {
    return isf ? ((const float*)p)[i] : bf2f(((const unsigned short*)p)[i]);
}

// ---------------------------------------------------------------------------
// Dtype probe: flag=1 -> inputs are f32; flag=0 -> bf16.
// ---------------------------------------------------------------------------
__global__ void detect_kernel(const void* x, int* flag) {
    const unsigned short* u = (const unsigned short*)x;
    int t = threadIdx.x;  // 64 threads
    int cnt = 0;
#pragma unroll
    for (int s = 0; s < 64; ++s) {
        unsigned short v = u[2 * (t * 64 + s)];
        int e = (v >> 7) & 0xFF;
        cnt += (e >= 0x8A || (e != 0 && e <= 0x6E)) ? 1 : 0;
    }
#pragma unroll
    for (int m = 1; m < 64; m <<= 1) cnt += __shfl_xor(cnt, m);
    if (t == 0) *flag = (cnt > 1024) ? 1 : 0;
}

// ---------------------------------------------------------------------------
// Convert the four 1024x1024 weights to bf16; blockIdx.y==4 builds RoPE tables.
// ---------------------------------------------------------------------------
__global__ __launch_bounds__(256) void cvt_w4_kernel(
    const void* Wq, const void* Wk, const void* Wv, const void* Wout,
    unsigned short* dq, unsigned short* dk, unsigned short* dv, unsigned short* dout,
    float* __restrict__ cosT, float* __restrict__ sinT,
    const int* flagp) {
    if (blockIdx.y == 4) {
        int idx = blockIdx.x * 256 + threadIdx.x;  // 0..262143 = 4096*64
        int l = idx >> 6, i = idx & 63;
        float invf = powf(10000.0f, -(float)i * (1.0f / 64.0f));
        float fr = (float)l * invf;
        cosT[idx] = cosf(fr);
        sinT[idx] = sinf(fr);
        return;
    }
    const bool isf = (*flagp != 0);
    const void* s;
    unsigned short* d;
    switch (blockIdx.y) {
        case 0: s = Wq; d = dq; break;
        case 1: s = Wk; d = dk; break;
        case 2: s = Wv; d = dv; break;
        default: s = Wout; d = dout; break;
    }
    size_t i = ((size_t)blockIdx.x * 256 + threadIdx.x) * 4;
#pragma unroll
    for (int r = 0; r < 4; ++r) d[i + r] = f2us(loadAny(s, i + r, isf));
}

// ---------------------------------------------------------------------------
// Convert gate weights into zero-padded [256][1024] bf16 Wg_pad (rows 0..23 =
// beta/ig/og, rows 24..255 zero) and biases (-> f32).
// ---------------------------------------------------------------------------
__global__ __launch_bounds__(256) void cvt_small_kernel(
    const void* Wbeta, const void* Wig, const void* Wog,
    const void* bbeta, const void* big, const void* bog, const void* bout,
    unsigned short* __restrict__ Wg_pad,
    float* dbb, float* dbi, float* dbo, float* dbout,
    const int* flagp) {
    const bool isf = (*flagp != 0);
    int gid = blockIdx.x * 256 + threadIdx.x;
    if (gid < 24576) {
        int seg = gid >> 13, off = gid & 8191;
        const void* s = (seg == 0) ? Wbeta : (seg == 1) ? Wig : Wog;
        Wg_pad[gid] = f2us(loadAny(s, off, isf));
    } else if (gid < 25624) {
        int j = gid - 24576;
        if (j < 8) dbb[j] = loadAny(bbeta, j, isf);
        else if (j < 16) dbi[j - 8] = loadAny(big, j - 8, isf);
        else if (j < 24) dbo[j - 16] = loadAny(bog, j - 16, isf);
        else if (j < 24 + 1024) dbout[j - 24] = loadAny(bout, j - 24, isf);
    } else {
        int z = gid - 25624;
        if (z < 29696) {  // (256-24)*1024/8
            uint4 zz = make_uint4(0, 0, 0, 0);
            *(uint4*)(Wg_pad + 24576 + (size_t)z * 8) = zz;
        }
    }
}

// ---------------------------------------------------------------------------
// Pure streaming RMSNorm: h = x*rsqrt(mean(x^2)+1e-6)*w (bf16 out).
// ---------------------------------------------------------------------------
__global__ __launch_bounds__(256) void rmsnorm_kernel(
    const void* __restrict__ xin, const void* __restrict__ win,
    __hip_bfloat16* __restrict__ h, const int* __restrict__ flagp) {
    const bool isf = (*flagp != 0);
    const int row = blockIdx.x;
    const int tid = threadIdx.x;
    const int lane = tid & 63, wave = tid >> 6;
    const size_t base = (size_t)row * HID;
    float x0, x1, x2, x3;
    if (isf) {
        float4 u = ((const float4*)((const float*)xin + base))[tid];
        x0 = u.x; x1 = u.y; x2 = u.z; x3 = u.w;
    } else {
        ushort4 u = ((const ushort4*)((const unsigned short*)xin + base))[tid];
        x0 = bf2f(u.x); x1 = bf2f(u.y); x2 = bf2f(u.z); x3 = bf2f(u.w);
    }
    float ss = x0 * x0 + x1 * x1 + x2 * x2 + x3 * x3;
#pragma unroll
    for (int m = 1; m < 64; m <<= 1) ss += __shfl_xor(ss, m);
    __shared__ float wsum[4];
    if (lane == 0) wsum[wave] = ss;
    __syncthreads();
    float tot = wsum[0] + wsum[1] + wsum[2] + wsum[3];
    float inv = rsqrtf(tot * (1.0f / HID) + 1e-6f);
    float w0, w1, w2, w3;
    if (isf) {
        float4 u = ((const float4*)win)[tid];
        w0 = u.x; w1 = u.y; w2 = u.z; w3 = u.w;
    } else {
        ushort4 u = ((const ushort4*)win)[tid];
        w0 = bf2f(u.x); w1 = bf2f(u.y); w2 = bf2f(u.z); w3 = bf2f(u.w);
    }
    ushort4 ho4;
    ho4.x = f2us(x0 * inv * w0);
    ho4.y = f2us(x1 * inv * w1);
    ho4.z = f2us(x2 * inv * w2);
    ho4.w = f2us(x3 * inv * w3);
    *(ushort4*)((unsigned short*)h + base + tid * 4) = ho4;
}

// ---------------------------------------------------------------------------
// 256x256 (BK=64) 8-wave GEMM core: register-held fragments + COUNTED vmcnt
// (T4) + minimum barriers.
//
// Ledger (per-thread loads, in-order vmcnt retirement):
//   enter tile t: outstanding {t.B1(2), t.A1(2)} = 4; A0,B0 certified.
//   ph0: read A0,B0; issue t+1.A0,B0 (->8); MFMA; vmcnt(6)+bar  => t.B1 ok
//   ph1: read B1;    issue t+1.B1    (->8); MFMA; vmcnt(6)+bar  => t.A1 ok
//   ph2: read A1;    issue t+1.A1    (->8); MFMA
//   ph3:                                    MFMA; vmcnt(4)+bar  => t+1.A0,B0
//   tail tile (no issues): vmcnt(2) / vmcnt(0) at ph0/ph1 closes.
// Stages only ever target the NEXT buffer (readable region sealed since the
// previous tile's close) -- the round-3-verified no-overwrite invariant.
// T2 granule-XOR swizzle and T5 setprio unchanged.
// ---------------------------------------------------------------------------
__device__ __forceinline__ void g256_stage_half(const unsigned short* __restrict__ src,
                                                unsigned short* lds, int tid) {
#pragma unroll
    for (int l = 0; l < 2; ++l) {
        int L = l * 512 + tid;          // 1024 granules = 128 rows x 8
        int r = L >> 3, g = L & 7;
        int gs = g ^ (r & 7);           // pre-swizzled global source
        __builtin_amdgcn_global_load_lds(
            (const __attribute__((address_space(1))) void*)(src + (size_t)r * HID + gs * 8),
            (__attribute__((address_space(3))) void*)(lds + L * 8), 16, 0, 0);
    }
}

#define G256_SEAL() __builtin_amdgcn_sched_barrier(0)
#define G256_BARRIER()            \
    do {                          \
        G256_SEAL();              \
        __builtin_amdgcn_s_barrier(); \
        G256_SEAL();              \
    } while (0)
#define G256_LGKM0()                                        \
    do {                                                    \
        asm volatile("s_waitcnt lgkmcnt(0)" ::: "memory");  \
        G256_SEAL();                                        \
    } while (0)
#define G256_VMCNT(n)                                            \
    do {                                                         \
        G256_SEAL();                                             \
        asm volatile("s_waitcnt vmcnt(" #n ")" ::: "memory");    \
        G256_SEAL();                                             \
    } while (0)

__device__ __forceinline__ void g256_read_A(const unsigned short* Ac, int mq,
                                            int wr, int lm, int lq, bf16x8 (&bA)[4][2]) {
#pragma unroll
    for (int i = 0; i < 4; ++i) {
        const int row = mq * 128 + wr * 64 + i * 16 + lm;
#pragma unroll
        for (int kk = 0; kk < 2; ++kk) {
            const int gsw = (kk * 4 + lq) ^ (lm & 7);
            bA[i][kk] = *(const bf16x8*)(const void*)(Ac + row * 64 + gsw * 8);
        }
    }
}
__device__ __forceinline__ void g256_read_B(const unsigned short* Bc, int nq,
                                            int wc, int lm, int lq, bf16x8 (&bB)[2][2]) {
#pragma unroll
    for (int j = 0; j < 2; ++j) {
        const int row = nq * 128 + wc * 32 + j * 16 + lm;
#pragma unroll
        for (int kk = 0; kk < 2; ++kk) {
            const int gsw = (kk * 4 + lq) ^ (lm & 7);
            bB[j][kk] = *(const bf16x8*)(const void*)(Bc + row * 64 + gsw * 8);
        }
    }
}
__device__ __forceinline__ void g256_mfma(int mq, int nq, const bf16x8 (&bA)[4][2],
                                          const bf16x8 (&bB)[2][2], f32x4 (&acc)[8][4]) {
    __builtin_amdgcn_s_setprio(1);
#pragma unroll
    for (int i = 0; i < 4; ++i)
#pragma unroll
        for (int j = 0; j < 2; ++j)
#pragma unroll
            for (int kk = 0; kk < 2; ++kk)
                acc[mq * 4 + i][nq * 2 + j] = __builtin_amdgcn_mfma_f32_16x16x32_bf16(
                    bA[i][kk], bB[j][kk], acc[mq * 4 + i][nq * 2 + j], 0, 0, 0);
    __builtin_amdgcn_s_setprio(0);
}

__device__ __forceinline__ void g256_core(const unsigned short* __restrict__ A,
                                          const unsigned short* __restrict__ W,
                                          unsigned short* As, unsigned short* Bs,
                                          int m0, int tid, f32x4 (&acc)[8][4]) {
    const int lane = tid & 63, wid = tid >> 6;
    const int wr = wid >> 2, wc = wid & 3;
    const int lm = lane & 15, lq = lane >> 4;
    // prologue: tile0 A0,B0,B1,A1 -> buf0; certify A0,B0; B1,A1 stay in flight.
    g256_stage_half(A + (size_t)m0 * HID, As, tid);                  // A0 (2)
    g256_stage_half(W, Bs, tid);                                     // B0 (2)
    g256_stage_half(W + (size_t)128 * HID, Bs + 8192, tid);          // B1 (2)
    g256_stage_half(A + (size_t)(m0 + 128) * HID, As + 8192, tid);   // A1 (2)
    G256_VMCNT(4);
    G256_BARRIER();
    for (int t = 0; t < GNT; ++t) {
        unsigned short* Ac = As + (t & 1) * 16384;
        unsigned short* Bc = Bs + (t & 1) * 16384;
        unsigned short* An = As + ((t & 1) ^ 1) * 16384;
        unsigned short* Bn = Bs + ((t & 1) ^ 1) * 16384;
        const int kn = (t + 1) * 64;
        const bool pf = (t + 1 < GNT);
        bf16x8 bA[4][2], bB0[2][2], bB1[2][2];
        // ---- ph0: read A0+B0 (certified); issue (t+1).A0,B0; MFMA ----
        g256_read_A(Ac, 0, wr, lm, lq, bA);
        g256_read_B(Bc, 0, wc, lm, lq, bB0);
        if (pf) {
            g256_stage_half(A + (size_t)m0 * HID + kn, An, tid);
            g256_stage_half(W + kn, Bn, tid);
        }
        G256_LGKM0();
        g256_mfma(0, 0, bA, bB0, acc);
        if (pf) G256_VMCNT(6); else G256_VMCNT(2);   // certify t.B1
        G256_BARRIER();
        // ---- ph1: read B1; issue (t+1).B1; MFMA ----
        g256_read_B(Bc, 1, wc, lm, lq, bB1);
        if (pf) g256_stage_half(W + (size_t)128 * HID + kn, Bn + 8192, tid);
        G256_LGKM0();
        g256_mfma(0, 1, bA, bB1, acc);
        if (pf) G256_VMCNT(6); else G256_VMCNT(0);   // certify t.A1
        G256_BARRIER();
        // ---- ph2: read A1; issue (t+1).A1; MFMA ----
        g256_read_A(Ac, 1, wr, lm, lq, bA);
        if (pf) g256_stage_half(A + (size_t)(m0 + 128) * HID + kn, An + 8192, tid);
        G256_LGKM0();
        g256_mfma(1, 0, bA, bB0, acc);
        // ---- ph3: MFMA only; certify (t+1).A0,B0 at tile close ----
        g256_mfma(1, 1, bA, bB1, acc);
        if (pf) G256_VMCNT(4);
        G256_BARRIER();
    }
}

// ---------------------------------------------------------------------------
// Merged QKV+gates GEMM: blockIdx.y in [0,13).  y<12 -> weight y>>2, column
// block (y&3)*256, bf16 C-write.  y==12 -> zero-padded gate weights; epilogue
// applies bias+sigmoid and scatters the 24 valid columns into fT/gT/oT.
// ---------------------------------------------------------------------------
__global__ __launch_bounds__(512) void gemm_qkv(const __hip_bfloat16* __restrict__ A,
                                                const unsigned short* __restrict__ Wqc,
                                                const unsigned short* __restrict__ Wkc,
                                                const unsigned short* __restrict__ Wvc,
                                                const unsigned short* __restrict__ Wg_pad,
                                                unsigned short* __restrict__ qb,
                                                unsigned short* __restrict__ kb,
                                                unsigned short* __restrict__ vb,
                                                const float* __restrict__ bbeta,
                                                const float* __restrict__ big,
                                                const float* __restrict__ bog,
                                                float* __restrict__ fT,
                                                float* __restrict__ gT,
                                                float* __restrict__ oT) {
    __shared__ __align__(16) unsigned short As[2 * 16384];
    __shared__ __align__(16) unsigned short Bs[2 * 16384];
    const int nblk = blockIdx.y;
    const int sel = nblk >> 2;           // 0,1,2 = q,k,v; 3 = gates
    const int nl0 = (nblk & 3) * 256;    // 0 for gate block
    const unsigned short* W =
        (sel == 0) ? Wqc + (size_t)nl0 * HID
      : (sel == 1) ? Wkc + (size_t)nl0 * HID
      : (sel == 2) ? Wvc + (size_t)nl0 * HID
                   : Wg_pad;
    const int tid = threadIdx.x;
    const int lane = tid & 63, wid = tid >> 6;
    const int wr = wid >> 2, wc = wid & 3;
    const int lm = lane & 15, lq = lane >> 4;
    const int m0 = blockIdx.x * 256;
    f32x4 acc[8][4] = {};
    g256_core((const unsigned short*)A, W, As, Bs, m0, tid, acc);
    if (sel < 3) {
        unsigned short* C = (sel == 0) ? qb : (sel == 1) ? kb : vb;
#pragma unroll
        for (int mq = 0; mq < 2; ++mq)
#pragma unroll
            for (int i = 0; i < 4; ++i)
#pragma unroll
                for (int nq = 0; nq < 2; ++nq)
#pragma unroll
                    for (int j = 0; j < 2; ++j) {
                        const int col = nl0 + nq * 128 + wc * 32 + j * 16 + lm;
#pragma unroll
                        for (int r = 0; r < 4; ++r) {
                            const int rowg = m0 + mq * 128 + wr * 64 + i * 16 + lq * 4 + r;
                            C[(size_t)rowg * HID + col] = f2us(acc[mq * 4 + i][nq * 2 + j][r]);
                        }
                    }
    } else {
        // gates: cols 0..23 valid (nq=0 quadrant only)
#pragma unroll
        for (int j = 0; j < 2; ++j) {
            const int col = wc * 32 + j * 16 + lm;  // nq=0 cols only
            if (col < 24) {
                const float bb = (col < 8) ? bbeta[col]
                               : (col < 16) ? big[col - 8]
                                            : bog[col - 16];
                const int hh = col & 7;
                float* dst = (col < 8) ? fT : (col < 16) ? gT : oT;
#pragma unroll
                for (int mq = 0; mq < 2; ++mq)
#pragma unroll
                    for (int i = 0; i < 4; ++i)
#pragma unroll
                        for (int r = 0; r < 4; ++r) {
                            const int rowg = m0 + mq * 128 + wr * 64 + i * 16 + lq * 4 + r;
                            const int b = rowg >> 12, l = rowg & (LQ - 1);
                            float s = acc[mq * 4 + i][j][r] + bb;  // nq=0 -> slot j, lane r
                            s = 1.0f / (1.0f + expf(-s));
                            dst[((size_t)(b * NHEAD + hh)) * LQ + l] = s;
                        }
            }
        }
    }
}

// ---------------------------------------------------------------------------
// Final GEMM on the 256^2 core: C = A W^T + bias; C f32 when (*flagp).
// ---------------------------------------------------------------------------
__global__ __launch_bounds__(512) void gemm_bt(const __hip_bfloat16* __restrict__ A,
                                               const __hip_bfloat16* __restrict__ W,
                                               const float* __restrict__ bias,
                                               void* __restrict__ C,
                                               const int* __restrict__ flagp) {
    __shared__ __align__(16) unsigned short As[2 * 16384];
    __shared__ __align__(16) unsigned short Bs[2 * 16384];
    const bool f32out = (*flagp != 0);
    const int tid = threadIdx.x;
    const int lane = tid & 63, wid = tid >> 6;
    const int wr = wid >> 2, wc = wid & 3;
    const int lm = lane & 15, lq = lane >> 4;
    const int m0 = blockIdx.x * 256;
    const int nl0 = blockIdx.y * 256;
    f32x4 acc[8][4] = {};
    g256_core((const unsigned short*)A, (const unsigned short*)W + (size_t)nl0 * HID,
              As, Bs, m0, tid, acc);
#pragma unroll
    for (int mq = 0; mq < 2; ++mq)
#pragma unroll
        for (int i = 0; i < 4; ++i)
#pragma unroll
            for (int nq = 0; nq < 2; ++nq)
#pragma unroll
                for (int j = 0; j < 2; ++j) {
                    const int col = nl0 + nq * 128 + wc * 32 + j * 16 + lm;
                    const float bv = bias[col];
#pragma unroll
                    for (int r = 0; r < 4; ++r) {
                        const int rowg = m0 + mq * 128 + wr * 64 + i * 16 + lq * 4 + r;
                        const size_t idx = (size_t)rowg * HID + col;
                        const float val = acc[mq * 4 + i][nq * 2 + j][r] + bv;
                        if (f32out) ((float*)C)[idx] = val;
                        else ((__hip_bfloat16*)C)[idx] = __float2bfloat16(val);
                    }
                }
}

// ---------------------------------------------------------------------------
// INTRA kernel + prep. Q is never staged to LDS: each lane builds its MFMA
// A-fragment of rope(q) in registers (pair i/i+64 lives in the same thread)
// and writes scaled qb back from the same registers. LDS = Kr+Vt+Sp ~46 KB
// -> 3 blocks/CU.
// ---------------------------------------------------------------------------
__global__ __launch_bounds__(256) void intra_kernel(
    unsigned short* __restrict__ qg, const unsigned short* __restrict__ kg,
    const unsigned short* __restrict__ vg,
    const float* __restrict__ fT, const float* __restrict__ gT, const float* __restrict__ oT,
    const float* __restrict__ cosT, const float* __restrict__ sinT,
    __hip_bfloat16* __restrict__ yb,
    unsigned short* __restrict__ ktg, float* __restrict__ cdecG) {
    const int chunk = blockIdx.x;        // 0..63
    const int bh = blockIdx.y;           // 0..31
    const int b = bh >> 3, hh = bh & 7;
    const int t0 = chunk * CCH;
    const int tid = threadIdx.x;
    const int lane = tid & 63, wave = tid >> 6;
    const int lm = lane & 15, lq = lane >> 4;
    __shared__ unsigned short Kr[64 * 136];
    __shared__ unsigned short Vt[128 * 72];
    __shared__ unsigned short Sp[64 * 72];
    __shared__ float Lp[64], aS[64], osh[64], w2s[64], qscs[64];

    // phase 0: gates + decay prefix (wave 0)
    if (tid < 64) {
        float f = fT[(size_t)bh * LQ + t0 + tid];
        float g = gT[(size_t)bh * LQ + t0 + tid];
        osh[tid] = oT[(size_t)bh * LQ + t0 + tid];
        float lf = __logf(f);
#pragma unroll
        for (int off = 1; off < 64; off <<= 1) {
            float v = __shfl_up(lf, off);
            if (lane >= off) lf += v;
        }
        float tot = __shfl(lf, 63);
        Lp[tid] = lf;
        aS[tid] = g * 0.08838834764831845f;  // g / sqrt(128)
        w2s[tid] = __expf(tot - lf) * (g * 0.08838834764831845f);
        qscs[tid] = __expf(lf);
        if (tid == 63) cdecG[bh * NCH + chunk] = __expf(lf);
    }
    __syncthreads();  // B0

    // phase 1a: Q fragments in registers + scaled write-back.
    bf16x8 af[4];
    {
        const int jr = 16 * wave + lm;
        const int gt = t0 + jr;
        const size_t qbase = ((size_t)(b * LQ + gt)) * HID + hh * DHEAD;
        uint4 qraw[4];
#pragma unroll
        for (int ks = 0; ks < 4; ++ks)
            qraw[ks] = *(const uint4*)(qg + qbase + ks * 32 + lq * 8);
        const unsigned short* q0 = (const unsigned short*)&qraw[0];
        const unsigned short* q1 = (const unsigned short*)&qraw[1];
        const unsigned short* q2 = (const unsigned short*)&qraw[2];
        const unsigned short* q3 = (const unsigned short*)&qraw[3];
        const float sc = qscs[jr];
        __align__(16) unsigned short fr[4][8];
        __align__(16) unsigned short qo[4][8];
#pragma unroll
        for (int u = 0; u < 8; ++u) {
            int i = lq * 8 + u;          // pair (i, i+64) for ks 0<->2
            int i2 = 32 + lq * 8 + u;    // pair for ks 1<->3
            float c0 = cosT[gt * 64 + i], s0 = sinT[gt * 64 + i];
            float c1 = cosT[gt * 64 + i2], s1 = sinT[gt * 64 + i2];
            float a = bf2f(q0[u]), bq = bf2f(q2[u]);
            float rc = a * c0 - bq * s0, rs = a * s0 + bq * c0;
            fr[0][u] = f2us(rc); fr[2][u] = f2us(rs);
            qo[0][u] = f2us(rc * sc); qo[2][u] = f2us(rs * sc);
            float a1 = bf2f(q1[u]), bq1 = bf2f(q3[u]);
            float rc1 = a1 * c1 - bq1 * s1, rs1 = a1 * s1 + bq1 * c1;
            fr[1][u] = f2us(rc1); fr[3][u] = f2us(rs1);
            qo[1][u] = f2us(rc1 * sc); qo[3][u] = f2us(rs1 * sc);
        }
#pragma unroll
        for (int ks = 0; ks < 4; ++ks) {
            af[ks] = *(const bf16x8*)fr[ks];
            *(uint4*)(qg + qbase + ks * 32 + lq * 8) = *(const uint4*)qo[ks];
        }
    }
    // phase 1b: rope-stage K into LDS
#pragma unroll
    for (int r = 0; r < 16; ++r) {
        int pid = r * 256 + tid;
        int t = pid >> 6, i = pid & 63;
        int gt = t0 + t;
        size_t gidx = ((size_t)(b * LQ + gt)) * HID + hh * DHEAD + i;
        float c = cosT[gt * 64 + i], s = sinT[gt * 64 + i];
        float k1 = bf2f(kg[gidx]), k2 = bf2f(kg[gidx + 64]);
        Kr[t * 136 + i] = f2us(k1 * c - k2 * s);
        Kr[t * 136 + i + 64] = f2us(k1 * s + k2 * c);
    }
    // stage V transposed: Vt[e][s]
#pragma unroll
    for (int r = 0; r < 32; ++r) {
        int lin = r * 256 + tid;
        int sI = lin >> 7, e = lin & 127;
        float val = bf2f(vg[((size_t)(b * LQ + t0 + sI)) * HID + hh * DHEAD + e]);
        Vt[e * 72 + sI] = f2us(val);
    }
    __syncthreads();  // B1

    // S = Q K^T (64x64, K=128); wave j-strip [16*wave,+16), Q from registers
    f32x4 sacc[4] = {};
#pragma unroll
    for (int ks = 0; ks < 4; ++ks) {
#pragma unroll
        for (int nt = 0; nt < 4; ++nt) {
            bf16x8 bf = *(const bf16x8*)(const void*)(Kr + (nt * 16 + lm) * 136 + ks * 32 + lq * 8);
            sacc[nt] = __builtin_amdgcn_mfma_f32_16x16x32_bf16(af[ks], bf, sacc[nt], 0, 0, 0);
        }
    }
    // mask + decay/gate scale, store S' bf16 [j][s]
#pragma unroll
    for (int nt = 0; nt < 4; ++nt) {
#pragma unroll
        for (int r = 0; r < 4; ++r) {
            int j = 16 * wave + lq * 4 + r;
            int s = nt * 16 + lm;
            float v = 0.0f;
            if (j >= s) v = sacc[nt][r] * __expf(Lp[j] - Lp[s]) * aS[s];
            Sp[j * 72 + s] = f2us(v);
        }
    }
    // PREP: KtG[ks][d][32] = w2_s * Kr[s][d]
    {
        unsigned short* krec = ktg + ((size_t)(bh * NCH + chunk)) * 8192;
#pragma unroll
        for (int r = 0; r < 2; ++r) {
            int lin16 = r * 256 + tid;
            int ks = lin16 >> 8;
            int d = (lin16 & 255) >> 1;
            int cc0 = (lin16 & 1) * 16;
            __align__(16) unsigned short out[16];
#pragma unroll
            for (int u = 0; u < 16; ++u) {
                int s = ks * 32 + cc0 + u;
                out[u] = f2us(w2s[s] * bf2f(Kr[s * 136 + d]));
            }
            uint4* dst = (uint4*)(krec + (size_t)lin16 * 16);
            dst[0] = *(const uint4*)(out);
            dst[1] = *(const uint4*)(out + 8);
        }
    }
    __syncthreads();  // B2

    // Y_intra = S' V  (64x128, K=64)
    f32x4 ya[8] = {};
#pragma unroll
    for (int ks = 0; ks < 2; ++ks) {
        bf16x8 afs = *(const bf16x8*)(const void*)(Sp + (16 * wave + lm) * 72 + ks * 32 + lq * 8);
#pragma unroll
        for (int nt = 0; nt < 8; ++nt) {
            bf16x8 bf = *(const bf16x8*)(const void*)(Vt + (nt * 16 + lm) * 72 + ks * 32 + lq * 8);
            ya[nt] = __builtin_amdgcn_mfma_f32_16x16x32_bf16(afs, bf, ya[nt], 0, 0, 0);
        }
    }
#pragma unroll
    for (int nt = 0; nt < 8; ++nt) {
#pragma unroll
        for (int r = 0; r < 4; ++r) {
            int j = 16 * wave + lq * 4 + r;
            int e = nt * 16 + lm;
            size_t row = (size_t)(b * LQ + t0 + j);
            yb[row * HID + hh * DHEAD + e] = __float2bfloat16(osh[j] * ya[nt][r]);
        }
    }
}

// ---------------------------------------------------------------------------
// INTER kernel: ONE barrier per chunk. State M double-buffered in LDS (read
// M[c&1], write M[(c+1)&1]) so no second barrier is needed; Q/K DMA for c+1
// issued AFTER the top barrier so it stays in flight through chunk c's
// compute and is drained by the NEXT barrier (true prefetch overlap).
// yb RMW values prefetched right after the barrier to hide their latency.
// ---------------------------------------------------------------------------
__global__ __launch_bounds__(256) void inter_kernel(
    const unsigned short* __restrict__ qs,   // exp(Lp_j)*rope(q), [row][128]
    const unsigned short* __restrict__ ktg,  // [bh][chunk][ks][d][32]
    const unsigned short* __restrict__ vg,
    const float* __restrict__ oT, const float* __restrict__ cdecG,
    unsigned short* __restrict__ yb) {
    const int bh = blockIdx.x;       // 0..31
    const int esplit = blockIdx.y;   // 0..7
    const int e0 = esplit * 16;
    const int b = bh >> 3, hh = bh & 7;
    const int tid = threadIdx.x;
    const int lane = tid & 63, wave = tid >> 6;
    const int lm = lane & 15, lq = lane >> 4;
    __shared__ __align__(16) unsigned short Qsl[2][8192];  // [ks(4)][j(64)][32]
    __shared__ __align__(16) unsigned short Ktl[2][8192];  // [ks(2)][d(128)][32]
    __shared__ __align__(16) unsigned short Vtl[2][1024];  // [ks(2)][e(16)][32]
    __shared__ __align__(16) float Ml[2][16 * 132];        // M^T [e][d], stride 132

    for (int i = tid; i < 16 * 132; i += 256) Ml[0][i] = 0.0f;

    const int jrow = tid >> 2;
    const int qcol = (tid & 3) * 8;
    // prologue: DMA chunk 0 into buf 0, VALU-stage V0
    {
        const unsigned short* qrow =
            qs + ((size_t)(b * LQ + jrow)) * HID + hh * DHEAD + qcol;
#pragma unroll
        for (int ks = 0; ks < 4; ++ks)
            __builtin_amdgcn_global_load_lds(
                (const __attribute__((address_space(1))) void*)(qrow + ks * 32),
                (__attribute__((address_space(3))) void*)(&Qsl[0][ks * 2048 + tid * 8]),
                16, 0, 0);
        const unsigned short* kbase = ktg + ((size_t)(bh * NCH)) * 8192 + tid * 8;
#pragma unroll
        for (int i = 0; i < 4; ++i)
            __builtin_amdgcn_global_load_lds(
                (const __attribute__((address_space(1))) void*)(kbase + i * 2048),
                (__attribute__((address_space(3))) void*)(&Ktl[0][i * 2048 + tid * 8]),
                16, 0, 0);
#pragma unroll
        for (int r = 0; r < 4; ++r) {
            int lin = r * 256 + tid;
            int s = lin >> 4, e = lin & 15;
            float val = bf2f(vg[((size_t)(b * LQ + s)) * HID + hh * DHEAD + e0 + e]);
            Vtl[0][(s >> 5) * 512 + e * 32 + (s & 31)] = f2us(val);
        }
    }

    for (int c = 0; c < NCH; ++c) {
        const int cur = c & 1, nxt = cur ^ 1;
        const int t0 = c * CCH;
        __syncthreads();  // drains chunk-c DMA (issued last iter), M[cur] visible
        // issue DMA for c+1 (drained at NEXT barrier -> overlaps this compute)
        if (c + 1 < NCH) {
            const int t0n = t0 + CCH;
            const unsigned short* qrow =
                qs + ((size_t)(b * LQ + t0n + jrow)) * HID + hh * DHEAD + qcol;
#pragma unroll
            for (int ks = 0; ks < 4; ++ks)
                __builtin_amdgcn_global_load_lds(
                    (const __attribute__((address_space(1))) void*)(qrow + ks * 32),
                    (__attribute__((address_space(3))) void*)(&Qsl[nxt][ks * 2048 + tid * 8]),
                    16, 0, 0);
            const unsigned short* kbase = ktg + ((size_t)(bh * NCH + c + 1)) * 8192 + tid * 8;
#pragma unroll
            for (int i = 0; i < 4; ++i)
                __builtin_amdgcn_global_load_lds(
                    (const __attribute__((address_space(1))) void*)(kbase + i * 2048),
                    (__attribute__((address_space(3))) void*)(&Ktl[nxt][i * 2048 + tid * 8]),
                    16, 0, 0);
        }
        // early yb/o prefetch (consumed after MFMAs)
        size_t yidx[4];
        unsigned short prevy[4];
        float osv[4];
#pragma unroll
        for (int r = 0; r < 4; ++r) {
            int j = 16 * wave + lq * 4 + r;
            yidx[r] = ((size_t)(b * LQ + t0 + j)) * HID + hh * DHEAD + e0 + lm;
            prevy[r] = yb[yidx[r]];
            osv[r] = oT[(size_t)bh * LQ + t0 + j];
        }
        const float cd = cdecG[bh * NCH + c];
        // U = K''^T V : wave d-strip [32*wave, +32)
        f32x4 uacc[2] = {};
#pragma unroll
        for (int ks = 0; ks < 2; ++ks) {
            bf16x8 bfv = *(const bf16x8*)(const void*)(&Vtl[cur][ks * 512 + lm * 32 + lq * 8]);
#pragma unroll
            for (int mt = 0; mt < 2; ++mt) {
                bf16x8 af = *(const bf16x8*)(const void*)(
                    &Ktl[cur][ks * 4096 + (32 * wave + 16 * mt + lm) * 32 + lq * 8]);
                uacc[mt] = __builtin_amdgcn_mfma_f32_16x16x32_bf16(af, bfv, uacc[mt], 0, 0, 0);
            }
        }
        // Y = Qs @ M[cur] : wave j-strip [16*wave, +16)
        f32x4 yacc = {};
#pragma unroll
        for (int ks = 0; ks < 4; ++ks) {
            bf16x8 af = *(const bf16x8*)(const void*)(
                &Qsl[cur][ks * 2048 + (16 * wave + lm) * 32 + lq * 8]);
            float4 m0 = *(const float4*)(const void*)(&Ml[cur][lm * 132 + ks * 32 + lq * 8]);
            float4 m1 = *(const float4*)(const void*)(&Ml[cur][lm * 132 + ks * 32 + lq * 8 + 4]);
            __align__(16) unsigned short tmp[8];
            tmp[0] = f2us(m0.x); tmp[1] = f2us(m0.y); tmp[2] = f2us(m0.z); tmp[3] = f2us(m0.w);
            tmp[4] = f2us(m1.x); tmp[5] = f2us(m1.y); tmp[6] = f2us(m1.z); tmp[7] = f2us(m1.w);
            bf16x8 bfm = *(const bf16x8*)tmp;
            yacc = __builtin_amdgcn_mfma_f32_16x16x32_bf16(af, bfm, yacc, 0, 0, 0);
        }
        // yb += o * Y_inter
#pragma unroll
        for (int r = 0; r < 4; ++r)
            yb[yidx[r]] = f2us(bf2f(prevy[r]) + osv[r] * yacc[r]);
        // VALU-stage V for chunk c+1 into nxt buffer
        if (c + 1 < NCH) {
            const int t0n = t0 + CCH;
#pragma unroll
            for (int r = 0; r < 4; ++r) {
                int lin = r * 256 + tid;
                int s = lin >> 4, e = lin & 15;
                float val = bf2f(vg[((size_t)(b * LQ + t0n + s)) * HID + hh * DHEAD + e0 + e]);
                Vtl[nxt][(s >> 5) * 512 + e * 32 + (s & 31)] = f2us(val);
            }
        }
        // M[nxt] = cd * M[cur] + U  (write other buffer -> no barrier needed)
#pragma unroll
        for (int mt = 0; mt < 2; ++mt)
#pragma unroll
            for (int r = 0; r < 4; ++r) {
                int d = 32 * wave + 16 * mt + lq * 4 + r;
                Ml[nxt][lm * 132 + d] = cd * Ml[cur][lm * 132 + d] + uacc[mt][r];
            }
    }
}

// ---------------------------------------------------------------------------
extern "C" void kernel_launch(void* const* d_in, const int* in_sizes, int n_in,
                              void* d_out, int out_size, void* d_ws, size_t ws_size,
                              hipStream_t stream) {
    const void* x      = d_in[0];
    const void* norm_w = d_in[1];
    const void* Wq     = d_in[2];
    const void* Wk     = d_in[3];
    const void* Wv     = d_in[4];
    const void* Wbeta  = d_in[5];
    const void* bbeta  = d_in[6];
    const void* Wig    = d_in[7];
    const void* big    = d_in[8];
    const void* Wog    = d_in[9];
    const void* bog    = d_in[10];
    const void* Wout   = d_in[11];
    const void* bout   = d_in[12];

    char* ws = (char*)d_ws;
    const size_t KB = 1024, MB = 1024 * 1024;
    int*   flag    = (int*)(ws + 0);
    float* bbeta_c = (float*)(ws + 1 * KB);
    float* big_c   = (float*)(ws + 1 * KB + 32);
    float* bog_c   = (float*)(ws + 1 * KB + 64);
    float* bout_c  = (float*)(ws + 4 * KB);
    float* cdecG   = (float*)(ws + 16 * KB);            // 8 KiB
    float* fT   = (float*)(ws + 1 * MB);
    float* gT   = (float*)(ws + 1 * MB + 512 * KB);
    float* oT   = (float*)(ws + 2 * MB);
    float* cosT = (float*)(ws + 2 * MB + 512 * KB);
    float* sinT = (float*)(ws + 3 * MB + 512 * KB);
    unsigned short* Wq_c   = (unsigned short*)(ws + 5 * MB);
    unsigned short* Wk_c   = (unsigned short*)(ws + 7 * MB);
    unsigned short* Wv_c   = (unsigned short*)(ws + 9 * MB);
    unsigned short* Wout_c = (unsigned short*)(ws + 11 * MB);
    unsigned short* Wg_pad = (unsigned short*)(ws + 13 * MB);  // 512 KiB padded gates
    __hip_bfloat16* h  = (__hip_bfloat16*)(ws + 16 * MB);   // 32 MiB; dead after QKV gemm
    unsigned short* ktg = (unsigned short*)(ws + 16 * MB);  // aliases h (32 MiB)
    unsigned short* qb = (unsigned short*)(ws + 48 * MB);
    unsigned short* kb = (unsigned short*)(ws + 80 * MB);
    unsigned short* vb = (unsigned short*)(ws + 112 * MB);
    __hip_bfloat16* yb = (__hip_bfloat16*)(ws + 144 * MB);

    detect_kernel<<<1, 64, 0, stream>>>(x, flag);
    cvt_w4_kernel<<<dim3(1024, 5), 256, 0, stream>>>(Wq, Wk, Wv, Wout,
                                                     Wq_c, Wk_c, Wv_c, Wout_c,
                                                     cosT, sinT, flag);
    cvt_small_kernel<<<217, 256, 0, stream>>>(Wbeta, Wig, Wog, bbeta, big, bog, bout,
                                              Wg_pad,
                                              bbeta_c, big_c, bog_c, bout_c, flag);
    rmsnorm_kernel<<<MROWS, 256, 0, stream>>>(x, norm_w, h, flag);

    gemm_qkv<<<dim3(MROWS / 256, 13), 512, 0, stream>>>(
        h, Wq_c, Wk_c, Wv_c, Wg_pad, qb, kb, vb,
        bbeta_c, big_c, bog_c, fT, gT, oT);

    intra_kernel<<<dim3(NCH, 32), 256, 0, stream>>>(qb, kb, vb, fT, gT, oT, cosT, sinT,
                                                    (__hip_bfloat16*)yb, ktg, cdecG);
    inter_kernel<<<dim3(32, 8), 256, 0, stream>>>(qb, ktg, vb, oT, cdecG,
                                                  (unsigned short*)yb);

    gemm_bt<<<dim3(MROWS / 256, HID / 256), 512, 0, stream>>>(
        (const __hip_bfloat16*)yb, (const __hip_bfloat16*)Wout_c, bout_c, d_out, flag);
}